// Round 1
// baseline (756.214 us; speedup 1.0000x reference)
//
#include <hip/hip_runtime.h>
#include <hip/hip_bf16.h>

#define T_SEQ 2048
#define HIDDEN_SZ 4096
#define NUM_HEADS 32
#define HEAD_DIM 128
#define KV_GROUPS 2
#define Q_SZ 4096          // NUM_HEADS*HEAD_DIM
#define KV_SZ 256          // KV_GROUPS*HEAD_DIM
#define QKV_DIM 4608       // Q_SZ + 2*KV_SZ

typedef __attribute__((ext_vector_type(8))) short bf16x8_t;   // 8 bf16 = 4 VGPR (A/B frag)
typedef __attribute__((ext_vector_type(4))) float f32x4_t;    // C/D frag

__device__ inline void store_c(float* p, float v) { *p = v; }
__device__ inline void store_c(__hip_bfloat16* p, float v) { *p = __float2bfloat16(v); }

// async global->LDS, 16B per lane; LDS dest = wave-uniform base + lane*16
#define GLDS16(gp, lp)                                                                  \
    __builtin_amdgcn_global_load_lds((const __attribute__((address_space(1))) unsigned int*)(gp), \
                                     (__attribute__((address_space(3))) unsigned int*)(lp), 16, 0, 0)

// ---------------- fp32 -> bf16 contiguous convert ----------------
__global__ __launch_bounds__(256) void convert_bf16_kernel(const float* __restrict__ in,
                                                           __hip_bfloat16* __restrict__ out,
                                                           int n) {
    int i = (blockIdx.x * 256 + threadIdx.x) * 4;
    if (i + 3 < n) {
        float4 v = *reinterpret_cast<const float4*>(in + i);
        alignas(8) __hip_bfloat16 tmp[4] = {__float2bfloat16(v.x), __float2bfloat16(v.y),
                                            __float2bfloat16(v.z), __float2bfloat16(v.w)};
        *reinterpret_cast<ushort4*>(out + i) = *reinterpret_cast<const ushort4*>(tmp);
    }
}

// ---------------- fp32 [R][C] -> bf16 [C][R] tile transpose (64x64, vectorized) ----------------
__global__ __launch_bounds__(256) void transpose_convert_kernel(const float* __restrict__ in,
                                                                __hip_bfloat16* __restrict__ out,
                                                                int R, int C) {
    __shared__ float tile[64][65];   // pad 65: column reads conflict-free
    const int tx = threadIdx.x & 15;   // 0..15
    const int ty = threadIdx.x >> 4;   // 0..15
    const int c0 = blockIdx.x * 64, r0 = blockIdx.y * 64;
    #pragma unroll
    for (int i = 0; i < 4; ++i) {
        int row = ty + 16 * i;
        float4 v = *reinterpret_cast<const float4*>(&in[(size_t)(r0 + row) * C + c0 + tx * 4]);
        tile[row][tx * 4 + 0] = v.x; tile[row][tx * 4 + 1] = v.y;
        tile[row][tx * 4 + 2] = v.z; tile[row][tx * 4 + 3] = v.w;
    }
    __syncthreads();
    #pragma unroll
    for (int i = 0; i < 4; ++i) {
        int ocol = ty + 16 * i;
        alignas(8) __hip_bfloat16 o[4];
        #pragma unroll
        for (int j = 0; j < 4; ++j) o[j] = __float2bfloat16(tile[tx * 4 + j][ocol]);
        *reinterpret_cast<ushort4*>(&out[(size_t)(c0 + ocol) * R + r0 + tx * 4]) =
            *reinterpret_cast<const ushort4*>(o);
    }
}

// ---------------- bf16 MFMA GEMM: C[M][N] = A[M][K] * BT[N][K]^T (+bias) ----------------
// 128x128 block tile, 4 waves (2x2), each wave 64x64 = 4x4 accums of 16x16, BK=32.
// m97 structure: global_load_lds width-16 staging into UNPADDED stride-32 LDS tiles.
template <typename OutT>
__global__ __launch_bounds__(256) void gemm_bf16_kernel(const __hip_bfloat16* __restrict__ A,
                                                        const __hip_bfloat16* __restrict__ BT,
                                                        const float* __restrict__ bias,
                                                        OutT* __restrict__ C,
                                                        int M, int N, int K) {
    constexpr int BM = 128, BN = 128, BK = 32;
    __shared__ __hip_bfloat16 lA[BM * BK];   // packed: row*32 + col (global_load_lds order)
    __shared__ __hip_bfloat16 lB[BN * BK];
    const int tid = threadIdx.x;
    const int bm = blockIdx.y * BM, bn = blockIdx.x * BN;
    const int wave = tid >> 6, lane = tid & 63;
    const int wr = wave >> 1, wc = wave & 1;
    const int n16 = lane & 15, quad = lane >> 4;
    const int lrow = lane >> 2;          // 0..15 within a 16-row chunk
    const int lcol = (lane & 3) * 8;     // elem col 0,8,16,24
    f32x4_t acc[4][4] = {};
    for (int kk = 0; kk < K; kk += BK) {
        // staging: 8 chunks of 1 KiB (16 rows x 64 B) per tile, 2 chunks per wave per tile
        #pragma unroll
        for (int p = 0; p < 2; ++p) {
            int ca = wave * 2 + p;                 // chunk 0..7
            int row = ca * 16 + lrow;
            GLDS16(&A[(size_t)(bm + row) * K + kk + lcol], &lA[ca * 512]);
            GLDS16(&BT[(size_t)(bn + row) * K + kk + lcol], &lB[ca * 512]);
        }
        __syncthreads();
        bf16x8_t af[4], bfr[4];
        #pragma unroll
        for (int i = 0; i < 4; ++i)
            af[i] = *reinterpret_cast<const bf16x8_t*>(&lA[(wr * 64 + i * 16 + n16) * BK + quad * 8]);
        #pragma unroll
        for (int j = 0; j < 4; ++j)
            bfr[j] = *reinterpret_cast<const bf16x8_t*>(&lB[(wc * 64 + j * 16 + n16) * BK + quad * 8]);
        #pragma unroll
        for (int i = 0; i < 4; ++i)
            #pragma unroll
            for (int j = 0; j < 4; ++j)
                acc[i][j] = __builtin_amdgcn_mfma_f32_16x16x32_bf16(af[i], bfr[j], acc[i][j], 0, 0, 0);
        __syncthreads();
    }
    #pragma unroll
    for (int i = 0; i < 4; ++i) {
        #pragma unroll
        for (int j = 0; j < 4; ++j) {
            int col = bn + wc * 64 + j * 16 + n16;
            float bv = bias ? bias[col] : 0.0f;
            #pragma unroll
            for (int r = 0; r < 4; ++r) {
                int row = bm + wr * 64 + i * 16 + quad * 4 + r;   // C/D: col=lane&15, row=quad*4+reg
                store_c(&C[(size_t)row * N + col], acc[i][j][r] + bv);
            }
        }
    }
}

// ---------------- RoPE + relayout: qkv[t][4608] -> q[h][t][d], k[g][t][d], vT[g][d][t] ----------------
// Q is pre-scaled by (1/sqrt(128))*log2(e) so flash attention can use raw exp2.
__global__ __launch_bounds__(64) void rope_reorg_kernel(const __hip_bfloat16* __restrict__ qkv,
                                                        const int* __restrict__ positions,
                                                        __hip_bfloat16* __restrict__ qo,
                                                        __hip_bfloat16* __restrict__ ko,
                                                        __hip_bfloat16* __restrict__ vTo) {
    const int t = blockIdx.x;
    const int u = blockIdx.y;       // 0..31 q heads, 32..33 k groups, 34..35 v groups
    const int tid = threadIdx.x;    // 0..63, handles dims (2*tid, 2*tid+1)
    const int d0 = tid * 2, d1 = d0 + 1;
    int col;
    if (u < 32) col = u * HEAD_DIM;
    else if (u < 34) col = Q_SZ + (u - 32) * HEAD_DIM;
    else col = Q_SZ + KV_SZ + (u - 34) * HEAD_DIM;
    float x0 = __bfloat162float(qkv[(size_t)t * QKV_DIM + col + d0]);
    float x1 = __bfloat162float(qkv[(size_t)t * QKV_DIM + col + d1]);
    float o0 = x0, o1 = x1;
    if (u < 34 && tid < 32) {  // rot_dim = 64: pairs i=0..31; dims 64..127 pass through
        float pos = (float)positions[t];
        float theta = exp2f(-(float)tid * 0.4152410118609203f);  // 10000^(-i/32)
        float ang = pos * theta;
        float sn, cs;
        sincosf(ang, &sn, &cs);
        o0 = x0 * cs - x1 * sn;
        o1 = x1 * cs + x0 * sn;
    }
    if (u < 32) {
        constexpr float qscale = 0.08838834764831845f * 1.4426950408889634f;  // rsqrt(128)*log2e
        __hip_bfloat16* dst = qo + ((size_t)u * T_SEQ + t) * HEAD_DIM;
        dst[d0] = __float2bfloat16(o0 * qscale);
        dst[d1] = __float2bfloat16(o1 * qscale);
    } else if (u < 34) {
        __hip_bfloat16* dst = ko + ((size_t)(u - 32) * T_SEQ + t) * HEAD_DIM;
        dst[d0] = __float2bfloat16(o0);
        dst[d1] = __float2bfloat16(o1);
    } else {
        int gg = u - 34;
        vTo[((size_t)gg * HEAD_DIM + d0) * T_SEQ + t] = __float2bfloat16(o0);
        vTo[((size_t)gg * HEAD_DIM + d1) * T_SEQ + t] = __float2bfloat16(o1);
    }
}

// ---------------- causal GQA flash attention (transposed, no K/V LDS, split-K balanced) ----------------
// S^T = K*Q^T with key-row permutation so S C-regs concatenate into the PV B-frag.
// Occupancy fix (this round): the old version ran 2048 waves (2/SIMD, Occupancy 21%,
// MfmaUtil 5.7%) — latency-bound. Now each balanced chunk pair (p, 127-p) is SPLIT
// across two waves by key range (flash-decoding style): wave half=0 takes the first
// nt/2 key tiles, half=1 the rest, merged in-block through LDS with online-softmax
// algebra. Every wave does ~32-33 tiles — exact balance with NO assumption about
// block->CU dispatch mapping (the round-3 failure mode) — and wave count doubles to
// 4096 = 4 waves/SIMD.
__global__ __launch_bounds__(256, 4) void flash_attn_kernel(const __hip_bfloat16* __restrict__ q,
                                                            const __hip_bfloat16* __restrict__ k,
                                                            const __hip_bfloat16* __restrict__ vT,
                                                            __hip_bfloat16* __restrict__ ctx) {
    const int h = blockIdx.y;           // 0..31
    const int g = h >> 4;               // kv group
    const int wave = threadIdx.x >> 6;
    const int lane = threadIdx.x & 63;
    const int n16 = lane & 15, quad = lane >> 4;
    const int wid = blockIdx.x * 4 + wave;   // 0..127
    const int pr = wid >> 1;                 // pair id 0..63
    const int half = wid & 1;                // 0 = early keys, 1 = late keys (incl. diagonal)
    const int pslot = wave >> 1;             // pair slot within block: 0..1
    const __hip_bfloat16* kbase = k + (size_t)g * T_SEQ * HEAD_DIM;
    const __hip_bfloat16* vbase = vT + (size_t)g * HEAD_DIM * T_SEQ;
    // A-frag row m=n16 -> key = kt*32 + (m>>2)*8 + c*4 + (m&3)
    const int krow_off = (n16 >> 2) * 8 + (n16 & 3);

    // merge buffers: stride 33 floats -> bank = (lane + j) % 32, conflict-free
    __shared__ float smO[2][64][33];
    __shared__ float smML[2][64][2];

    for (int pass = 0; pass < 2; ++pass) {
        const int chunk = pass ? (127 - pr) : pr;    // paired light+heavy: 65-66 tiles/pair
        const int qrow0 = chunk * 16;
        const int nt = (chunk >> 1) + 1;             // key tiles for this chunk
        const int ktA = half ? (nt >> 1) : 0;        // this wave's [ktA, ktB) tile range
        const int ktB = half ? nt : (nt >> 1);
        const int qg = qrow0 + n16;

        // Q B-frags: B[n=q(n16)][k=d(quad*8+j)], 4 frags over d=128
        const __hip_bfloat16* qrow = q + ((size_t)h * T_SEQ + qg) * HEAD_DIM;
        bf16x8_t qf[4];
        #pragma unroll
        for (int f = 0; f < 4; ++f)
            qf[f] = *reinterpret_cast<const bf16x8_t*>(qrow + f * 32 + quad * 8);

        f32x4_t accO[8] = {};
        float m_ = -1e30f, l_ = 0.0f;

        if (ktA < ktB) {
            bf16x8_t kf[2][4];
            #pragma unroll
            for (int c = 0; c < 2; ++c)
                #pragma unroll
                for (int f = 0; f < 4; ++f)
                    kf[c][f] = *reinterpret_cast<const bf16x8_t*>(
                        kbase + (size_t)(ktA * 32 + krow_off + c * 4) * HEAD_DIM + f * 32 + quad * 8);

            for (int kt = ktA; kt < ktB; ++kt) {
                // QK^T (transposed): s[c] rows = keys quad*8+c*4+r, cols = q
                f32x4_t s[2] = {};
                #pragma unroll
                for (int c = 0; c < 2; ++c)
                    #pragma unroll
                    for (int f = 0; f < 4; ++f)
                        s[c] = __builtin_amdgcn_mfma_f32_16x16x32_bf16(kf[c][f], qf[f], s[c], 0, 0, 0);
                // prefetch next K tile (WAR on kf orders these after the MFMAs)
                if (kt + 1 < ktB) {
                    int ktn = kt + 1;
                    #pragma unroll
                    for (int c = 0; c < 2; ++c)
                        #pragma unroll
                        for (int f = 0; f < 4; ++f)
                            kf[c][f] = *reinterpret_cast<const bf16x8_t*>(
                                kbase + (size_t)(ktn * 32 + krow_off + c * 4) * HEAD_DIM + f * 32 + quad * 8);
                }
                // V A-frags: A[m=d(n16)][k=key(quad*8+j)] — issued early, consumed after softmax
                bf16x8_t vf[8];
                #pragma unroll
                for (int dt = 0; dt < 8; ++dt)
                    vf[dt] = *reinterpret_cast<const bf16x8_t*>(
                        vbase + (size_t)(dt * 16 + n16) * T_SEQ + kt * 32 + quad * 8);

                // causal mask (only tiles crossing the diagonal)
                if (kt * 32 + 31 > qrow0) {
                    #pragma unroll
                    for (int c = 0; c < 2; ++c)
                        #pragma unroll
                        for (int r = 0; r < 4; ++r)
                            if (kt * 32 + quad * 8 + c * 4 + r > qg) s[c][r] = -1e30f;
                }
                // per-lane max over this lane's 8 keys, then 2 shuffles across quads
                float xm = fmaxf(fmaxf(fmaxf(s[0][0], s[0][1]), fmaxf(s[0][2], s[0][3])),
                                 fmaxf(fmaxf(s[1][0], s[1][1]), fmaxf(s[1][2], s[1][3])));
                xm = fmaxf(xm, __shfl_xor(xm, 16, 64));
                xm = fmaxf(xm, __shfl_xor(xm, 32, 64));
                float mn = fmaxf(m_, xm);
                float alpha = __builtin_amdgcn_exp2f(m_ - mn);
                m_ = mn;
                float p[2][4];
                #pragma unroll
                for (int c = 0; c < 2; ++c)
                    #pragma unroll
                    for (int r = 0; r < 4; ++r)
                        p[c][r] = __builtin_amdgcn_exp2f(s[c][r] - mn);
                // pack P^T into the K=32 B-frag: j=0..3 -> tile0, j=4..7 -> tile1
                union { bf16x8_t v; __hip_bfloat16 e[8]; } pf;
                #pragma unroll
                for (int c = 0; c < 2; ++c)
                    #pragma unroll
                    for (int r = 0; r < 4; ++r)
                        pf.e[c * 4 + r] = __float2bfloat16(p[c][r]);
                // rescale O^T by per-lane scalar alpha (skip when no lane's max moved)
                if (__any(alpha < 1.0f)) {
                    #pragma unroll
                    for (int dt = 0; dt < 8; ++dt)
                        #pragma unroll
                        for (int r = 0; r < 4; ++r) accO[dt][r] *= alpha;
                }
                // PV: O^T[d][q] += V^T[d][key] * P^T[key][q]
                #pragma unroll
                for (int dt = 0; dt < 8; ++dt)
                    accO[dt] = __builtin_amdgcn_mfma_f32_16x16x32_bf16(vf[dt], pf.v, accO[dt], 0, 0, 0);
                // l update (independent of PV; scheduler overlaps)
                float xs = ((p[0][0] + p[0][1]) + (p[0][2] + p[0][3])) +
                           ((p[1][0] + p[1][1]) + (p[1][2] + p[1][3]));
                xs += __shfl_xor(xs, 16, 64);
                xs += __shfl_xor(xs, 32, 64);
                l_ = l_ * alpha + xs;
            }
        }

        // ---- merge the two key-halves of this pair through LDS ----
        if (half) {
            #pragma unroll
            for (int dt = 0; dt < 8; ++dt)
                #pragma unroll
                for (int r = 0; r < 4; ++r) smO[pslot][lane][dt * 4 + r] = accO[dt][r];
            smML[pslot][lane][0] = m_;
            smML[pslot][lane][1] = l_;
        }
        __syncthreads();
        if (!half) {
            // half=1 always has >=1 tile (it owns the diagonal) -> mB finite, lB > 0.
            // half=0 may be empty (nt==1): m_=-1e30 -> aA underflows to exactly 0.
            float mB = smML[pslot][lane][0], lB = smML[pslot][lane][1];
            float mN = fmaxf(m_, mB);
            float aA = __builtin_amdgcn_exp2f(m_ - mN);
            float aB = __builtin_amdgcn_exp2f(mB - mN);
            float inv = 1.0f / (l_ * aA + lB * aB);
            #pragma unroll
            for (int dt = 0; dt < 8; ++dt) {
                alignas(8) __hip_bfloat16 o[4];
                #pragma unroll
                for (int r = 0; r < 4; ++r)
                    o[r] = __float2bfloat16((accO[dt][r] * aA + smO[pslot][lane][dt * 4 + r] * aB) * inv);
                // O^T[d][q]: lane writes 4 consecutive d at row t=qg
                *reinterpret_cast<ushort4*>(&ctx[(size_t)qg * Q_SZ + h * HEAD_DIM + dt * 16 + quad * 4]) =
                    *reinterpret_cast<const ushort4*>(o);
            }
        }
        __syncthreads();   // smO/smML reused next pass
    }
}

extern "C" void kernel_launch(void* const* d_in, const int* in_sizes, int n_in,
                              void* d_out, int out_size, void* d_ws, size_t ws_size,
                              hipStream_t stream) {
    (void)in_sizes; (void)n_in; (void)out_size; (void)ws_size;
    const int*   positions = (const int*)d_in[0];
    const float* hidden    = (const float*)d_in[1];
    const float* w_qkv     = (const float*)d_in[2];
    const float* b_qkv     = (const float*)d_in[3];
    const float* w_dense   = (const float*)d_in[4];
    float* out = (float*)d_out;

    char* ws = (char*)d_ws;
    __hip_bfloat16* h_bf   = (__hip_bfloat16*)ws; ws += (size_t)T_SEQ * HIDDEN_SZ * 2;
    __hip_bfloat16* wqkvT  = (__hip_bfloat16*)ws; ws += (size_t)QKV_DIM * HIDDEN_SZ * 2;
    __hip_bfloat16* wdT    = (__hip_bfloat16*)ws; ws += (size_t)HIDDEN_SZ * HIDDEN_SZ * 2;
    __hip_bfloat16* qkv_bf = (__hip_bfloat16*)ws; ws += (size_t)T_SEQ * QKV_DIM * 2;
    __hip_bfloat16* q_bf   = (__hip_bfloat16*)ws; ws += (size_t)NUM_HEADS * T_SEQ * HEAD_DIM * 2;
    __hip_bfloat16* k_bf   = (__hip_bfloat16*)ws; ws += (size_t)KV_GROUPS * T_SEQ * HEAD_DIM * 2;
    __hip_bfloat16* vT_bf  = (__hip_bfloat16*)ws; ws += (size_t)KV_GROUPS * HEAD_DIM * T_SEQ * 2;
    __hip_bfloat16* ctx_bf = h_bf;  // h_bf dead after QKV GEMM; reuse for ctx

    // 1) hidden fp32 -> bf16
    convert_bf16_kernel<<<(T_SEQ * HIDDEN_SZ) / (256 * 4), 256, 0, stream>>>(hidden, h_bf, T_SEQ * HIDDEN_SZ);
    // 2) weights fp32 [K][N] -> bf16 [N][K]
    transpose_convert_kernel<<<dim3(QKV_DIM / 64, HIDDEN_SZ / 64), 256, 0, stream>>>(w_qkv, wqkvT, HIDDEN_SZ, QKV_DIM);
    transpose_convert_kernel<<<dim3(HIDDEN_SZ / 64, HIDDEN_SZ / 64), 256, 0, stream>>>(w_dense, wdT, HIDDEN_SZ, HIDDEN_SZ);
    // 3) QKV GEMM (+bias) -> bf16 qkv
    gemm_bf16_kernel<__hip_bfloat16><<<dim3(QKV_DIM / 128, T_SEQ / 128), 256, 0, stream>>>(
        h_bf, wqkvT, b_qkv, qkv_bf, T_SEQ, QKV_DIM, HIDDEN_SZ);
    // 4) RoPE + relayout (Q pre-scaled by rsqrt(128)*log2e)
    rope_reorg_kernel<<<dim3(T_SEQ, NUM_HEADS + 2 * KV_GROUPS), 64, 0, stream>>>(
        qkv_bf, positions, q_bf, k_bf, vT_bf);
    // 5) causal GQA flash attention (split-K, 4 waves/SIMD) -> ctx bf16 [t][h*128+d]
    flash_attn_kernel<<<dim3(32, NUM_HEADS), 256, 0, stream>>>(q_bf, k_bf, vT_bf, ctx_bf);
    // 6) dense GEMM -> fp32 out
    gemm_bf16_kernel<float><<<dim3(HIDDEN_SZ / 128, T_SEQ / 128), 256, 0, stream>>>(
        ctx_bf, wdT, nullptr, out, T_SEQ, HIDDEN_SZ, HIDDEN_SZ);
}

// Round 2
// 691.739 us; speedup vs baseline: 1.0932x; 1.0932x over previous
//
#include <hip/hip_runtime.h>
#include <hip/hip_bf16.h>

#define T_SEQ 2048
#define HIDDEN_SZ 4096
#define NUM_HEADS 32
#define HEAD_DIM 128
#define KV_GROUPS 2
#define Q_SZ 4096          // NUM_HEADS*HEAD_DIM
#define KV_SZ 256          // KV_GROUPS*HEAD_DIM
#define QKV_DIM 4608       // Q_SZ + 2*KV_SZ

typedef __attribute__((ext_vector_type(8))) short bf16x8_t;   // 8 bf16 = 4 VGPR (A/B frag)
typedef __attribute__((ext_vector_type(4))) float f32x4_t;    // C/D frag

__device__ inline void store_c(float* p, float v) { *p = v; }
__device__ inline void store_c(__hip_bfloat16* p, float v) { *p = __float2bfloat16(v); }

// async global->LDS, 16B per lane; LDS dest = wave-uniform base + lane*16
#define GLDS16(gp, lp)                                                                  \
    __builtin_amdgcn_global_load_lds((const __attribute__((address_space(1))) unsigned int*)(gp), \
                                     (__attribute__((address_space(3))) unsigned int*)(lp), 16, 0, 0)

// ---------------- fp32 -> bf16 contiguous convert ----------------
__global__ __launch_bounds__(256) void convert_bf16_kernel(const float* __restrict__ in,
                                                           __hip_bfloat16* __restrict__ out,
                                                           int n) {
    int i = (blockIdx.x * 256 + threadIdx.x) * 4;
    if (i + 3 < n) {
        float4 v = *reinterpret_cast<const float4*>(in + i);
        alignas(8) __hip_bfloat16 tmp[4] = {__float2bfloat16(v.x), __float2bfloat16(v.y),
                                            __float2bfloat16(v.z), __float2bfloat16(v.w)};
        *reinterpret_cast<ushort4*>(out + i) = *reinterpret_cast<const ushort4*>(tmp);
    }
}

// ---------------- fp32 [R][C] -> bf16 [C][R] tile transpose (64x64, vectorized) ----------------
__global__ __launch_bounds__(256) void transpose_convert_kernel(const float* __restrict__ in,
                                                                __hip_bfloat16* __restrict__ out,
                                                                int R, int C) {
    __shared__ float tile[64][65];   // pad 65: column reads conflict-free
    const int tx = threadIdx.x & 15;   // 0..15
    const int ty = threadIdx.x >> 4;   // 0..15
    const int c0 = blockIdx.x * 64, r0 = blockIdx.y * 64;
    #pragma unroll
    for (int i = 0; i < 4; ++i) {
        int row = ty + 16 * i;
        float4 v = *reinterpret_cast<const float4*>(&in[(size_t)(r0 + row) * C + c0 + tx * 4]);
        tile[row][tx * 4 + 0] = v.x; tile[row][tx * 4 + 1] = v.y;
        tile[row][tx * 4 + 2] = v.z; tile[row][tx * 4 + 3] = v.w;
    }
    __syncthreads();
    #pragma unroll
    for (int i = 0; i < 4; ++i) {
        int ocol = ty + 16 * i;
        alignas(8) __hip_bfloat16 o[4];
        #pragma unroll
        for (int j = 0; j < 4; ++j) o[j] = __float2bfloat16(tile[tx * 4 + j][ocol]);
        *reinterpret_cast<ushort4*>(&out[(size_t)(c0 + ocol) * R + r0 + tx * 4]) =
            *reinterpret_cast<const ushort4*>(o);
    }
}

// ---------------- bf16 MFMA GEMM: C[M][N] = A[M][K] * BT[N][K]^T (+bias) ----------------
// 128x128 block tile, 4 waves (2x2), each wave 64x64 = 4x4 accums of 16x16, BK=32.
// m97 structure: global_load_lds width-16 staging into UNPADDED stride-32 LDS tiles.
template <typename OutT>
__global__ __launch_bounds__(256) void gemm_bf16_kernel(const __hip_bfloat16* __restrict__ A,
                                                        const __hip_bfloat16* __restrict__ BT,
                                                        const float* __restrict__ bias,
                                                        OutT* __restrict__ C,
                                                        int M, int N, int K) {
    constexpr int BM = 128, BN = 128, BK = 32;
    __shared__ __hip_bfloat16 lA[BM * BK];   // packed: row*32 + col (global_load_lds order)
    __shared__ __hip_bfloat16 lB[BN * BK];
    const int tid = threadIdx.x;
    const int bm = blockIdx.y * BM, bn = blockIdx.x * BN;
    const int wave = tid >> 6, lane = tid & 63;
    const int wr = wave >> 1, wc = wave & 1;
    const int n16 = lane & 15, quad = lane >> 4;
    const int lrow = lane >> 2;          // 0..15 within a 16-row chunk
    const int lcol = (lane & 3) * 8;     // elem col 0,8,16,24
    f32x4_t acc[4][4] = {};
    for (int kk = 0; kk < K; kk += BK) {
        // staging: 8 chunks of 1 KiB (16 rows x 64 B) per tile, 2 chunks per wave per tile
        #pragma unroll
        for (int p = 0; p < 2; ++p) {
            int ca = wave * 2 + p;                 // chunk 0..7
            int row = ca * 16 + lrow;
            GLDS16(&A[(size_t)(bm + row) * K + kk + lcol], &lA[ca * 512]);
            GLDS16(&BT[(size_t)(bn + row) * K + kk + lcol], &lB[ca * 512]);
        }
        __syncthreads();
        bf16x8_t af[4], bfr[4];
        #pragma unroll
        for (int i = 0; i < 4; ++i)
            af[i] = *reinterpret_cast<const bf16x8_t*>(&lA[(wr * 64 + i * 16 + n16) * BK + quad * 8]);
        #pragma unroll
        for (int j = 0; j < 4; ++j)
            bfr[j] = *reinterpret_cast<const bf16x8_t*>(&lB[(wc * 64 + j * 16 + n16) * BK + quad * 8]);
        #pragma unroll
        for (int i = 0; i < 4; ++i)
            #pragma unroll
            for (int j = 0; j < 4; ++j)
                acc[i][j] = __builtin_amdgcn_mfma_f32_16x16x32_bf16(af[i], bfr[j], acc[i][j], 0, 0, 0);
        __syncthreads();
    }
    #pragma unroll
    for (int i = 0; i < 4; ++i) {
        #pragma unroll
        for (int j = 0; j < 4; ++j) {
            int col = bn + wc * 64 + j * 16 + n16;
            float bv = bias ? bias[col] : 0.0f;
            #pragma unroll
            for (int r = 0; r < 4; ++r) {
                int row = bm + wr * 64 + i * 16 + quad * 4 + r;   // C/D: col=lane&15, row=quad*4+reg
                store_c(&C[(size_t)row * N + col], acc[i][j][r] + bv);
            }
        }
    }
}

// ---------------- RoPE + relayout: qkv[t][4608] -> q[h][t][d], k[g][t][d], vT[g][d][t] ----------------
// Q is pre-scaled by (1/sqrt(128))*log2(e) so flash attention can use raw exp2.
__global__ __launch_bounds__(64) void rope_reorg_kernel(const __hip_bfloat16* __restrict__ qkv,
                                                        const int* __restrict__ positions,
                                                        __hip_bfloat16* __restrict__ qo,
                                                        __hip_bfloat16* __restrict__ ko,
                                                        __hip_bfloat16* __restrict__ vTo) {
    const int t = blockIdx.x;
    const int u = blockIdx.y;       // 0..31 q heads, 32..33 k groups, 34..35 v groups
    const int tid = threadIdx.x;    // 0..63, handles dims (2*tid, 2*tid+1)
    const int d0 = tid * 2, d1 = d0 + 1;
    int col;
    if (u < 32) col = u * HEAD_DIM;
    else if (u < 34) col = Q_SZ + (u - 32) * HEAD_DIM;
    else col = Q_SZ + KV_SZ + (u - 34) * HEAD_DIM;
    float x0 = __bfloat162float(qkv[(size_t)t * QKV_DIM + col + d0]);
    float x1 = __bfloat162float(qkv[(size_t)t * QKV_DIM + col + d1]);
    float o0 = x0, o1 = x1;
    if (u < 34 && tid < 32) {  // rot_dim = 64: pairs i=0..31; dims 64..127 pass through
        float pos = (float)positions[t];
        float theta = exp2f(-(float)tid * 0.4152410118609203f);  // 10000^(-i/32)
        float ang = pos * theta;
        float sn, cs;
        sincosf(ang, &sn, &cs);
        o0 = x0 * cs - x1 * sn;
        o1 = x1 * cs + x0 * sn;
    }
    if (u < 32) {
        constexpr float qscale = 0.08838834764831845f * 1.4426950408889634f;  // rsqrt(128)*log2e
        __hip_bfloat16* dst = qo + ((size_t)u * T_SEQ + t) * HEAD_DIM;
        dst[d0] = __float2bfloat16(o0 * qscale);
        dst[d1] = __float2bfloat16(o1 * qscale);
    } else if (u < 34) {
        __hip_bfloat16* dst = ko + ((size_t)(u - 32) * T_SEQ + t) * HEAD_DIM;
        dst[d0] = __float2bfloat16(o0);
        dst[d1] = __float2bfloat16(o1);
    } else {
        int gg = u - 34;
        vTo[((size_t)gg * HEAD_DIM + d0) * T_SEQ + t] = __float2bfloat16(o0);
        vTo[((size_t)gg * HEAD_DIM + d1) * T_SEQ + t] = __float2bfloat16(o1);
    }
}

// ---------------- causal GQA flash attention (transposed, no K/V LDS, split-K balanced) ----------------
// S^T = K*Q^T with key-row permutation so S C-regs concatenate into the PV B-frag.
// Split-K (flash-decoding style): each balanced chunk pair (p, 127-p) is split across
// two waves by key range; merged in-block through LDS with online-softmax algebra.
// Every wave does ~32-33 tiles — exact balance, no dispatch-mapping assumptions —
// grid 1024 blocks * 4 waves = 4096 waves = 16/CU (occupancy cap 50%).
// NOTE round-1 lesson: do NOT add a min-waves __launch_bounds__ arg here. Capping the
// allocator at 128 (or 64) VGPRs spills accO/kf to scratch -> 370 MB of HBM spill
// traffic, dur 245->320 µs. Natural allocation is ~92-100 VGPR, which already admits
// 5 waves/SIMD; occupancy is grid-limited, not VGPR-limited.
__global__ __launch_bounds__(256) void flash_attn_kernel(const __hip_bfloat16* __restrict__ q,
                                                         const __hip_bfloat16* __restrict__ k,
                                                         const __hip_bfloat16* __restrict__ vT,
                                                         __hip_bfloat16* __restrict__ ctx) {
    const int h = blockIdx.y;           // 0..31
    const int g = h >> 4;               // kv group
    const int wave = threadIdx.x >> 6;
    const int lane = threadIdx.x & 63;
    const int n16 = lane & 15, quad = lane >> 4;
    const int wid = blockIdx.x * 4 + wave;   // 0..127
    const int pr = wid >> 1;                 // pair id 0..63
    const int half = wid & 1;                // 0 = early keys, 1 = late keys (incl. diagonal)
    const int pslot = wave >> 1;             // pair slot within block: 0..1
    const __hip_bfloat16* kbase = k + (size_t)g * T_SEQ * HEAD_DIM;
    const __hip_bfloat16* vbase = vT + (size_t)g * HEAD_DIM * T_SEQ;
    // A-frag row m=n16 -> key = kt*32 + (m>>2)*8 + c*4 + (m&3)
    const int krow_off = (n16 >> 2) * 8 + (n16 & 3);

    // merge buffers: stride 33 floats -> bank = (lane + j) % 32, conflict-free
    __shared__ float smO[2][64][33];
    __shared__ float smML[2][64][2];

    for (int pass = 0; pass < 2; ++pass) {
        const int chunk = pass ? (127 - pr) : pr;    // paired light+heavy: 65-66 tiles/pair
        const int qrow0 = chunk * 16;
        const int nt = (chunk >> 1) + 1;             // key tiles for this chunk
        const int ktA = half ? (nt >> 1) : 0;        // this wave's [ktA, ktB) tile range
        const int ktB = half ? nt : (nt >> 1);
        const int qg = qrow0 + n16;

        // Q B-frags: B[n=q(n16)][k=d(quad*8+j)], 4 frags over d=128
        const __hip_bfloat16* qrow = q + ((size_t)h * T_SEQ + qg) * HEAD_DIM;
        bf16x8_t qf[4];
        #pragma unroll
        for (int f = 0; f < 4; ++f)
            qf[f] = *reinterpret_cast<const bf16x8_t*>(qrow + f * 32 + quad * 8);

        f32x4_t accO[8] = {};
        float m_ = -1e30f, l_ = 0.0f;

        if (ktA < ktB) {
            bf16x8_t kf[2][4];
            #pragma unroll
            for (int c = 0; c < 2; ++c)
                #pragma unroll
                for (int f = 0; f < 4; ++f)
                    kf[c][f] = *reinterpret_cast<const bf16x8_t*>(
                        kbase + (size_t)(ktA * 32 + krow_off + c * 4) * HEAD_DIM + f * 32 + quad * 8);

            for (int kt = ktA; kt < ktB; ++kt) {
                // QK^T (transposed): s[c] rows = keys quad*8+c*4+r, cols = q
                f32x4_t s[2] = {};
                #pragma unroll
                for (int c = 0; c < 2; ++c)
                    #pragma unroll
                    for (int f = 0; f < 4; ++f)
                        s[c] = __builtin_amdgcn_mfma_f32_16x16x32_bf16(kf[c][f], qf[f], s[c], 0, 0, 0);
                // prefetch next K tile (WAR on kf orders these after the MFMAs)
                if (kt + 1 < ktB) {
                    int ktn = kt + 1;
                    #pragma unroll
                    for (int c = 0; c < 2; ++c)
                        #pragma unroll
                        for (int f = 0; f < 4; ++f)
                            kf[c][f] = *reinterpret_cast<const bf16x8_t*>(
                                kbase + (size_t)(ktn * 32 + krow_off + c * 4) * HEAD_DIM + f * 32 + quad * 8);
                }
                // V A-frags: A[m=d(n16)][k=key(quad*8+j)] — issued early, consumed after softmax
                bf16x8_t vf[8];
                #pragma unroll
                for (int dt = 0; dt < 8; ++dt)
                    vf[dt] = *reinterpret_cast<const bf16x8_t*>(
                        vbase + (size_t)(dt * 16 + n16) * T_SEQ + kt * 32 + quad * 8);

                // causal mask (only tiles crossing the diagonal)
                if (kt * 32 + 31 > qrow0) {
                    #pragma unroll
                    for (int c = 0; c < 2; ++c)
                        #pragma unroll
                        for (int r = 0; r < 4; ++r)
                            if (kt * 32 + quad * 8 + c * 4 + r > qg) s[c][r] = -1e30f;
                }
                // per-lane max over this lane's 8 keys, then 2 shuffles across quads
                float xm = fmaxf(fmaxf(fmaxf(s[0][0], s[0][1]), fmaxf(s[0][2], s[0][3])),
                                 fmaxf(fmaxf(s[1][0], s[1][1]), fmaxf(s[1][2], s[1][3])));
                xm = fmaxf(xm, __shfl_xor(xm, 16, 64));
                xm = fmaxf(xm, __shfl_xor(xm, 32, 64));
                float mn = fmaxf(m_, xm);
                float alpha = __builtin_amdgcn_exp2f(m_ - mn);
                m_ = mn;
                float p[2][4];
                #pragma unroll
                for (int c = 0; c < 2; ++c)
                    #pragma unroll
                    for (int r = 0; r < 4; ++r)
                        p[c][r] = __builtin_amdgcn_exp2f(s[c][r] - mn);
                // pack P^T into the K=32 B-frag: j=0..3 -> tile0, j=4..7 -> tile1
                union { bf16x8_t v; __hip_bfloat16 e[8]; } pf;
                #pragma unroll
                for (int c = 0; c < 2; ++c)
                    #pragma unroll
                    for (int r = 0; r < 4; ++r)
                        pf.e[c * 4 + r] = __float2bfloat16(p[c][r]);
                // rescale O^T by per-lane scalar alpha (skip when no lane's max moved)
                if (__any(alpha < 1.0f)) {
                    #pragma unroll
                    for (int dt = 0; dt < 8; ++dt)
                        #pragma unroll
                        for (int r = 0; r < 4; ++r) accO[dt][r] *= alpha;
                }
                // PV: O^T[d][q] += V^T[d][key] * P^T[key][q]
                #pragma unroll
                for (int dt = 0; dt < 8; ++dt)
                    accO[dt] = __builtin_amdgcn_mfma_f32_16x16x32_bf16(vf[dt], pf.v, accO[dt], 0, 0, 0);
                // l update (independent of PV; scheduler overlaps)
                float xs = ((p[0][0] + p[0][1]) + (p[0][2] + p[0][3])) +
                           ((p[1][0] + p[1][1]) + (p[1][2] + p[1][3]));
                xs += __shfl_xor(xs, 16, 64);
                xs += __shfl_xor(xs, 32, 64);
                l_ = l_ * alpha + xs;
            }
        }

        // ---- merge the two key-halves of this pair through LDS ----
        if (half) {
            #pragma unroll
            for (int dt = 0; dt < 8; ++dt)
                #pragma unroll
                for (int r = 0; r < 4; ++r) smO[pslot][lane][dt * 4 + r] = accO[dt][r];
            smML[pslot][lane][0] = m_;
            smML[pslot][lane][1] = l_;
        }
        __syncthreads();
        if (!half) {
            // half=1 always has >=1 tile (it owns the diagonal) -> mB finite, lB > 0.
            // half=0 may be empty (nt==1): m_=-1e30 -> aA underflows to exactly 0.
            float mB = smML[pslot][lane][0], lB = smML[pslot][lane][1];
            float mN = fmaxf(m_, mB);
            float aA = __builtin_amdgcn_exp2f(m_ - mN);
            float aB = __builtin_amdgcn_exp2f(mB - mN);
            float inv = 1.0f / (l_ * aA + lB * aB);
            #pragma unroll
            for (int dt = 0; dt < 8; ++dt) {
                alignas(8) __hip_bfloat16 o[4];
                #pragma unroll
                for (int r = 0; r < 4; ++r)
                    o[r] = __float2bfloat16((accO[dt][r] * aA + smO[pslot][lane][dt * 4 + r] * aB) * inv);
                // O^T[d][q]: lane writes 4 consecutive d at row t=qg
                *reinterpret_cast<ushort4*>(&ctx[(size_t)qg * Q_SZ + h * HEAD_DIM + dt * 16 + quad * 4]) =
                    *reinterpret_cast<const ushort4*>(o);
            }
        }
        __syncthreads();   // smO/smML reused next pass
    }
}

extern "C" void kernel_launch(void* const* d_in, const int* in_sizes, int n_in,
                              void* d_out, int out_size, void* d_ws, size_t ws_size,
                              hipStream_t stream) {
    (void)in_sizes; (void)n_in; (void)out_size; (void)ws_size;
    const int*   positions = (const int*)d_in[0];
    const float* hidden    = (const float*)d_in[1];
    const float* w_qkv     = (const float*)d_in[2];
    const float* b_qkv     = (const float*)d_in[3];
    const float* w_dense   = (const float*)d_in[4];
    float* out = (float*)d_out;

    char* ws = (char*)d_ws;
    __hip_bfloat16* h_bf   = (__hip_bfloat16*)ws; ws += (size_t)T_SEQ * HIDDEN_SZ * 2;
    __hip_bfloat16* wqkvT  = (__hip_bfloat16*)ws; ws += (size_t)QKV_DIM * HIDDEN_SZ * 2;
    __hip_bfloat16* wdT    = (__hip_bfloat16*)ws; ws += (size_t)HIDDEN_SZ * HIDDEN_SZ * 2;
    __hip_bfloat16* qkv_bf = (__hip_bfloat16*)ws; ws += (size_t)T_SEQ * QKV_DIM * 2;
    __hip_bfloat16* q_bf   = (__hip_bfloat16*)ws; ws += (size_t)NUM_HEADS * T_SEQ * HEAD_DIM * 2;
    __hip_bfloat16* k_bf   = (__hip_bfloat16*)ws; ws += (size_t)KV_GROUPS * T_SEQ * HEAD_DIM * 2;
    __hip_bfloat16* vT_bf  = (__hip_bfloat16*)ws; ws += (size_t)KV_GROUPS * HEAD_DIM * T_SEQ * 2;
    __hip_bfloat16* ctx_bf = h_bf;  // h_bf dead after QKV GEMM; reuse for ctx

    // 1) hidden fp32 -> bf16
    convert_bf16_kernel<<<(T_SEQ * HIDDEN_SZ) / (256 * 4), 256, 0, stream>>>(hidden, h_bf, T_SEQ * HIDDEN_SZ);
    // 2) weights fp32 [K][N] -> bf16 [N][K]
    transpose_convert_kernel<<<dim3(QKV_DIM / 64, HIDDEN_SZ / 64), 256, 0, stream>>>(w_qkv, wqkvT, HIDDEN_SZ, QKV_DIM);
    transpose_convert_kernel<<<dim3(HIDDEN_SZ / 64, HIDDEN_SZ / 64), 256, 0, stream>>>(w_dense, wdT, HIDDEN_SZ, HIDDEN_SZ);
    // 3) QKV GEMM (+bias) -> bf16 qkv
    gemm_bf16_kernel<__hip_bfloat16><<<dim3(QKV_DIM / 128, T_SEQ / 128), 256, 0, stream>>>(
        h_bf, wqkvT, b_qkv, qkv_bf, T_SEQ, QKV_DIM, HIDDEN_SZ);
    // 4) RoPE + relayout (Q pre-scaled by rsqrt(128)*log2e)
    rope_reorg_kernel<<<dim3(T_SEQ, NUM_HEADS + 2 * KV_GROUPS), 64, 0, stream>>>(
        qkv_bf, positions, q_bf, k_bf, vT_bf);
    // 5) causal GQA flash attention (split-K, grid-limited occupancy ~50%) -> ctx bf16
    flash_attn_kernel<<<dim3(32, NUM_HEADS), 256, 0, stream>>>(q_bf, k_bf, vT_bf, ctx_bf);
    // 6) dense GEMM -> fp32 out
    gemm_bf16_kernel<float><<<dim3(HIDDEN_SZ / 128, T_SEQ / 128), 256, 0, stream>>>(
        ctx_bf, wdT, nullptr, out, T_SEQ, HIDDEN_SZ, HIDDEN_SZ);
}

// Round 3
// 536.518 us; speedup vs baseline: 1.4095x; 1.2893x over previous
//
#include <hip/hip_runtime.h>
#include <hip/hip_bf16.h>

#define T_SEQ 2048
#define HIDDEN_SZ 4096
#define NUM_HEADS 32
#define HEAD_DIM 128
#define KV_GROUPS 2
#define Q_SZ 4096          // NUM_HEADS*HEAD_DIM
#define KV_SZ 256          // KV_GROUPS*HEAD_DIM
#define QKV_DIM 4608       // Q_SZ + 2*KV_SZ

typedef __attribute__((ext_vector_type(8))) short bf16x8_t;   // 8 bf16 = 4 VGPR (A/B frag)
typedef __attribute__((ext_vector_type(4))) float f32x4_t;    // C/D frag

__device__ inline void store_c(float* p, float v) { *p = v; }
__device__ inline void store_c(__hip_bfloat16* p, float v) { *p = __float2bfloat16(v); }

// async global->LDS, 16B per lane; LDS dest = wave-uniform base + lane*16
#define GLDS16(gp, lp)                                                                  \
    __builtin_amdgcn_global_load_lds((const __attribute__((address_space(1))) unsigned int*)(gp), \
                                     (__attribute__((address_space(3))) unsigned int*)(lp), 16, 0, 0)

// ---------------- fp32 -> bf16 contiguous convert ----------------
__global__ __launch_bounds__(256) void convert_bf16_kernel(const float* __restrict__ in,
                                                           __hip_bfloat16* __restrict__ out,
                                                           int n) {
    int i = (blockIdx.x * 256 + threadIdx.x) * 4;
    if (i + 3 < n) {
        float4 v = *reinterpret_cast<const float4*>(in + i);
        alignas(8) __hip_bfloat16 tmp[4] = {__float2bfloat16(v.x), __float2bfloat16(v.y),
                                            __float2bfloat16(v.z), __float2bfloat16(v.w)};
        *reinterpret_cast<ushort4*>(out + i) = *reinterpret_cast<const ushort4*>(tmp);
    }
}

// ---------------- fp32 [R][C] -> bf16 [C][R] tile transpose (64x64, vectorized) ----------------
__global__ __launch_bounds__(256) void transpose_convert_kernel(const float* __restrict__ in,
                                                                __hip_bfloat16* __restrict__ out,
                                                                int R, int C) {
    __shared__ float tile[64][65];   // pad 65: column reads conflict-free
    const int tx = threadIdx.x & 15;   // 0..15
    const int ty = threadIdx.x >> 4;   // 0..15
    const int c0 = blockIdx.x * 64, r0 = blockIdx.y * 64;
    #pragma unroll
    for (int i = 0; i < 4; ++i) {
        int row = ty + 16 * i;
        float4 v = *reinterpret_cast<const float4*>(&in[(size_t)(r0 + row) * C + c0 + tx * 4]);
        tile[row][tx * 4 + 0] = v.x; tile[row][tx * 4 + 1] = v.y;
        tile[row][tx * 4 + 2] = v.z; tile[row][tx * 4 + 3] = v.w;
    }
    __syncthreads();
    #pragma unroll
    for (int i = 0; i < 4; ++i) {
        int ocol = ty + 16 * i;
        alignas(8) __hip_bfloat16 o[4];
        #pragma unroll
        for (int j = 0; j < 4; ++j) o[j] = __float2bfloat16(tile[tx * 4 + j][ocol]);
        *reinterpret_cast<ushort4*>(&out[(size_t)(c0 + ocol) * R + r0 + tx * 4]) =
            *reinterpret_cast<const ushort4*>(o);
    }
}

// ---------------- bf16 MFMA GEMM: C[M][N] = A[M][K] * BT[N][K]^T (+bias) ----------------
// 128x128 block tile, 4 waves (2x2), each wave 64x64 = 4x4 accums of 16x16, BK=32.
// m97 structure: global_load_lds width-16 staging into UNPADDED stride-32 LDS tiles.
template <typename OutT>
__global__ __launch_bounds__(256) void gemm_bf16_kernel(const __hip_bfloat16* __restrict__ A,
                                                        const __hip_bfloat16* __restrict__ BT,
                                                        const float* __restrict__ bias,
                                                        OutT* __restrict__ C,
                                                        int M, int N, int K) {
    constexpr int BM = 128, BN = 128, BK = 32;
    __shared__ __hip_bfloat16 lA[BM * BK];   // packed: row*32 + col (global_load_lds order)
    __shared__ __hip_bfloat16 lB[BN * BK];
    const int tid = threadIdx.x;
    const int bm = blockIdx.y * BM, bn = blockIdx.x * BN;
    const int wave = tid >> 6, lane = tid & 63;
    const int wr = wave >> 1, wc = wave & 1;
    const int n16 = lane & 15, quad = lane >> 4;
    const int lrow = lane >> 2;          // 0..15 within a 16-row chunk
    const int lcol = (lane & 3) * 8;     // elem col 0,8,16,24
    f32x4_t acc[4][4] = {};
    for (int kk = 0; kk < K; kk += BK) {
        // staging: 8 chunks of 1 KiB (16 rows x 64 B) per tile, 2 chunks per wave per tile
        #pragma unroll
        for (int p = 0; p < 2; ++p) {
            int ca = wave * 2 + p;                 // chunk 0..7
            int row = ca * 16 + lrow;
            GLDS16(&A[(size_t)(bm + row) * K + kk + lcol], &lA[ca * 512]);
            GLDS16(&BT[(size_t)(bn + row) * K + kk + lcol], &lB[ca * 512]);
        }
        __syncthreads();
        bf16x8_t af[4], bfr[4];
        #pragma unroll
        for (int i = 0; i < 4; ++i)
            af[i] = *reinterpret_cast<const bf16x8_t*>(&lA[(wr * 64 + i * 16 + n16) * BK + quad * 8]);
        #pragma unroll
        for (int j = 0; j < 4; ++j)
            bfr[j] = *reinterpret_cast<const bf16x8_t*>(&lB[(wc * 64 + j * 16 + n16) * BK + quad * 8]);
        #pragma unroll
        for (int i = 0; i < 4; ++i)
            #pragma unroll
            for (int j = 0; j < 4; ++j)
                acc[i][j] = __builtin_amdgcn_mfma_f32_16x16x32_bf16(af[i], bfr[j], acc[i][j], 0, 0, 0);
        __syncthreads();
    }
    #pragma unroll
    for (int i = 0; i < 4; ++i) {
        #pragma unroll
        for (int j = 0; j < 4; ++j) {
            int col = bn + wc * 64 + j * 16 + n16;
            float bv = bias ? bias[col] : 0.0f;
            #pragma unroll
            for (int r = 0; r < 4; ++r) {
                int row = bm + wr * 64 + i * 16 + quad * 4 + r;   // C/D: col=lane&15, row=quad*4+reg
                store_c(&C[(size_t)row * N + col], acc[i][j][r] + bv);
            }
        }
    }
}

// ---------------- RoPE + relayout ----------------
// qkv[t][4608] -> q[h][t][d]  (row-major, as before)
//                 kfrag[g][kt][c][f][lane][8]  (frag-major: flash kf loads are contiguous)
//                 vfrag[g][kt][dt][lane][8]    (frag-major: flash vf loads are contiguous)
// Frag-major inverts the flash fragment mapping (round-2 verified formulas):
//   K: lane(n16,quad) elem j of kf[c][f] = K[kt*32 + (n16>>2)*8 + c*4 + (n16&3)][f*32+quad*8+j]
//   V: lane(n16,quad) elem j of vf[dt]   = V[kt*32 + quad*8 + j][dt*16 + n16]
// Q is pre-scaled by (1/sqrt(128))*log2(e) so flash attention can use raw exp2.
__global__ __launch_bounds__(64) void rope_reorg_kernel(const __hip_bfloat16* __restrict__ qkv,
                                                        const int* __restrict__ positions,
                                                        __hip_bfloat16* __restrict__ qo,
                                                        __hip_bfloat16* __restrict__ ko,
                                                        __hip_bfloat16* __restrict__ vTo) {
    const int t = blockIdx.x;
    const int u = blockIdx.y;       // 0..31 q heads, 32..33 k groups, 34..35 v groups
    const int tid = threadIdx.x;    // 0..63, handles dims (2*tid, 2*tid+1)
    const int d0 = tid * 2, d1 = d0 + 1;
    int col;
    if (u < 32) col = u * HEAD_DIM;
    else if (u < 34) col = Q_SZ + (u - 32) * HEAD_DIM;
    else col = Q_SZ + KV_SZ + (u - 34) * HEAD_DIM;
    float x0 = __bfloat162float(qkv[(size_t)t * QKV_DIM + col + d0]);
    float x1 = __bfloat162float(qkv[(size_t)t * QKV_DIM + col + d1]);
    float o0 = x0, o1 = x1;
    if (u < 34 && tid < 32) {  // rot_dim = 64: pairs i=0..31; dims 64..127 pass through
        float pos = (float)positions[t];
        float theta = exp2f(-(float)tid * 0.4152410118609203f);  // 10000^(-i/32)
        float ang = pos * theta;
        float sn, cs;
        sincosf(ang, &sn, &cs);
        o0 = x0 * cs - x1 * sn;
        o1 = x1 * cs + x0 * sn;
    }
    if (u < 32) {
        constexpr float qscale = 0.08838834764831845f * 1.4426950408889634f;  // rsqrt(128)*log2e
        __hip_bfloat16* dst = qo + ((size_t)u * T_SEQ + t) * HEAD_DIM;
        dst[d0] = __float2bfloat16(o0 * qscale);
        dst[d1] = __float2bfloat16(o1 * qscale);
    } else if (u < 34) {
        // K frag-major. key t: kt=t>>5, kw=t&31 -> c=(kw>>2)&1, n16=((kw>>3)<<2)|(kw&3)
        // dim d0 (even): f=d0>>5, quad=(d0>>3)&3, j=d0&7 (d1 = same frag, j+1)
        const int gg = u - 32;
        const int kt = t >> 5, kw = t & 31;
        const int c = (kw >> 2) & 1;
        const int n16k = ((kw >> 3) << 2) | (kw & 3);
        const int f = d0 >> 5, quad = (d0 >> 3) & 3, j0 = d0 & 7;
        __hip_bfloat16* dst = ko + (size_t)gg * (T_SEQ * HEAD_DIM) +
                              ((size_t)(((kt * 2 + c) * 4 + f)) << 9) + (quad * 16 + n16k) * 8 + j0;
        dst[0] = __float2bfloat16(o0);
        dst[1] = __float2bfloat16(o1);
    } else {
        // V frag-major. key t: kt=t>>5, kw=t&31 -> quad=kw>>3, j=kw&7
        // dim d0 (even): dt=d0>>4, n16=d0&15 (d1 -> n16+1, idx+8)
        const int gg = u - 34;
        const int kt = t >> 5, kw = t & 31;
        const int quad = kw >> 3, j = kw & 7;
        const int dt0 = d0 >> 4, n0 = d0 & 15;
        __hip_bfloat16* dst = vTo + (size_t)gg * (T_SEQ * HEAD_DIM) +
                              ((size_t)(kt * 8 + dt0) << 9) + (quad * 16 + n0) * 8 + j;
        dst[0] = __float2bfloat16(o0);
        dst[8] = __float2bfloat16(o1);
    }
}

// ---------------- causal GQA flash attention (frag-major K/V, split-K balanced) ----------------
// S^T = K*Q^T with key-row permutation so S C-regs concatenate into the PV B-frag.
// Round-2 lesson: the old row-major K / transposed-V loads made every kf/vf fragment
// read a 16-cache-line GATHER (16 rows x 16B, stride 256B/4KB) -> 256 line transactions
// per tile per wave -> MSHR-serialized at L2 latency; per-tile cost ~4600 cyc was
// invariant to wave count (round 0 vs round 2 identical). Fix: K/V stored frag-major
// by rope_reorg so each kf/vf load instruction reads 64 lanes x 16B = 1KB CONTIGUOUS.
// Register contents are bit-identical to the round-2 verified kernel.
// Split-K (flash-decoding): chunk pair (p,127-p) split across two waves by key range,
// merged in-block via LDS online-softmax algebra; every wave ~32-33 tiles, exact
// balance, no dispatch-mapping assumptions. No min-waves launch bound (round-1 spill).
__global__ __launch_bounds__(256) void flash_attn_kernel(const __hip_bfloat16* __restrict__ q,
                                                         const __hip_bfloat16* __restrict__ k,
                                                         const __hip_bfloat16* __restrict__ vT,
                                                         __hip_bfloat16* __restrict__ ctx) {
    const int h = blockIdx.y;           // 0..31
    const int g = h >> 4;               // kv group
    const int wave = threadIdx.x >> 6;
    const int lane = threadIdx.x & 63;
    const int n16 = lane & 15, quad = lane >> 4;
    const int wid = blockIdx.x * 4 + wave;   // 0..127
    const int pr = wid >> 1;                 // pair id 0..63
    const int half = wid & 1;                // 0 = early keys, 1 = late keys (incl. diagonal)
    const int pslot = wave >> 1;             // pair slot within block: 0..1
    const __hip_bfloat16* kbase = k + (size_t)g * (T_SEQ * HEAD_DIM) + (size_t)lane * 8;
    const __hip_bfloat16* vbase = vT + (size_t)g * (T_SEQ * HEAD_DIM) + (size_t)lane * 8;

    // merge buffers: stride 33 floats -> bank = (lane + j) % 32, conflict-free
    __shared__ float smO[2][64][33];
    __shared__ float smML[2][64][2];

    for (int pass = 0; pass < 2; ++pass) {
        const int chunk = pass ? (127 - pr) : pr;    // paired light+heavy: 65-66 tiles/pair
        const int qrow0 = chunk * 16;
        const int nt = (chunk >> 1) + 1;             // key tiles for this chunk
        const int ktA = half ? (nt >> 1) : 0;        // this wave's [ktA, ktB) tile range
        const int ktB = half ? nt : (nt >> 1);
        const int qg = qrow0 + n16;

        // Q B-frags: B[n=q(n16)][k=d(quad*8+j)], 4 frags over d=128
        const __hip_bfloat16* qrow = q + ((size_t)h * T_SEQ + qg) * HEAD_DIM;
        bf16x8_t qf[4];
        #pragma unroll
        for (int f = 0; f < 4; ++f)
            qf[f] = *reinterpret_cast<const bf16x8_t*>(qrow + f * 32 + quad * 8);

        f32x4_t accO[8] = {};
        float m_ = -1e30f, l_ = 0.0f;

        if (ktA < ktB) {
            bf16x8_t kf[2][4];
            #pragma unroll
            for (int c = 0; c < 2; ++c)
                #pragma unroll
                for (int f = 0; f < 4; ++f)
                    kf[c][f] = *reinterpret_cast<const bf16x8_t*>(
                        kbase + ((size_t)((ktA * 2 + c) * 4 + f) << 9));

            for (int kt = ktA; kt < ktB; ++kt) {
                // QK^T (transposed): s[c] rows = keys quad*8+c*4+r, cols = q
                f32x4_t s[2] = {};
                #pragma unroll
                for (int c = 0; c < 2; ++c)
                    #pragma unroll
                    for (int f = 0; f < 4; ++f)
                        s[c] = __builtin_amdgcn_mfma_f32_16x16x32_bf16(kf[c][f], qf[f], s[c], 0, 0, 0);
                // prefetch next K tile (WAR on kf orders these after the MFMAs)
                if (kt + 1 < ktB) {
                    int ktn = kt + 1;
                    #pragma unroll
                    for (int c = 0; c < 2; ++c)
                        #pragma unroll
                        for (int f = 0; f < 4; ++f)
                            kf[c][f] = *reinterpret_cast<const bf16x8_t*>(
                                kbase + ((size_t)((ktn * 2 + c) * 4 + f) << 9));
                }
                // V A-frags: A[m=d(n16)][k=key(quad*8+j)] — issued early, consumed after softmax
                bf16x8_t vf[8];
                #pragma unroll
                for (int dt = 0; dt < 8; ++dt)
                    vf[dt] = *reinterpret_cast<const bf16x8_t*>(
                        vbase + ((size_t)(kt * 8 + dt) << 9));

                // causal mask (only tiles crossing the diagonal)
                if (kt * 32 + 31 > qrow0) {
                    #pragma unroll
                    for (int c = 0; c < 2; ++c)
                        #pragma unroll
                        for (int r = 0; r < 4; ++r)
                            if (kt * 32 + quad * 8 + c * 4 + r > qg) s[c][r] = -1e30f;
                }
                // per-lane max over this lane's 8 keys, then 2 shuffles across quads
                float xm = fmaxf(fmaxf(fmaxf(s[0][0], s[0][1]), fmaxf(s[0][2], s[0][3])),
                                 fmaxf(fmaxf(s[1][0], s[1][1]), fmaxf(s[1][2], s[1][3])));
                xm = fmaxf(xm, __shfl_xor(xm, 16, 64));
                xm = fmaxf(xm, __shfl_xor(xm, 32, 64));
                float mn = fmaxf(m_, xm);
                float alpha = __builtin_amdgcn_exp2f(m_ - mn);
                m_ = mn;
                float p[2][4];
                #pragma unroll
                for (int c = 0; c < 2; ++c)
                    #pragma unroll
                    for (int r = 0; r < 4; ++r)
                        p[c][r] = __builtin_amdgcn_exp2f(s[c][r] - mn);
                // pack P^T into the K=32 B-frag: j=0..3 -> tile0, j=4..7 -> tile1
                union { bf16x8_t v; __hip_bfloat16 e[8]; } pf;
                #pragma unroll
                for (int c = 0; c < 2; ++c)
                    #pragma unroll
                    for (int r = 0; r < 4; ++r)
                        pf.e[c * 4 + r] = __float2bfloat16(p[c][r]);
                // rescale O^T by per-lane scalar alpha (skip when no lane's max moved)
                if (__any(alpha < 1.0f)) {
                    #pragma unroll
                    for (int dt = 0; dt < 8; ++dt)
                        #pragma unroll
                        for (int r = 0; r < 4; ++r) accO[dt][r] *= alpha;
                }
                // PV: O^T[d][q] += V^T[d][key] * P^T[key][q]
                #pragma unroll
                for (int dt = 0; dt < 8; ++dt)
                    accO[dt] = __builtin_amdgcn_mfma_f32_16x16x32_bf16(vf[dt], pf.v, accO[dt], 0, 0, 0);
                // l update (independent of PV; scheduler overlaps)
                float xs = ((p[0][0] + p[0][1]) + (p[0][2] + p[0][3])) +
                           ((p[1][0] + p[1][1]) + (p[1][2] + p[1][3]));
                xs += __shfl_xor(xs, 16, 64);
                xs += __shfl_xor(xs, 32, 64);
                l_ = l_ * alpha + xs;
            }
        }

        // ---- merge the two key-halves of this pair through LDS ----
        if (half) {
            #pragma unroll
            for (int dt = 0; dt < 8; ++dt)
                #pragma unroll
                for (int r = 0; r < 4; ++r) smO[pslot][lane][dt * 4 + r] = accO[dt][r];
            smML[pslot][lane][0] = m_;
            smML[pslot][lane][1] = l_;
        }
        __syncthreads();
        if (!half) {
            // half=1 always has >=1 tile (it owns the diagonal) -> mB finite, lB > 0.
            // half=0 may be empty (nt==1): m_=-1e30 -> aA underflows to exactly 0.
            float mB = smML[pslot][lane][0], lB = smML[pslot][lane][1];
            float mN = fmaxf(m_, mB);
            float aA = __builtin_amdgcn_exp2f(m_ - mN);
            float aB = __builtin_amdgcn_exp2f(mB - mN);
            float inv = 1.0f / (l_ * aA + lB * aB);
            #pragma unroll
            for (int dt = 0; dt < 8; ++dt) {
                alignas(8) __hip_bfloat16 o[4];
                #pragma unroll
                for (int r = 0; r < 4; ++r)
                    o[r] = __float2bfloat16((accO[dt][r] * aA + smO[pslot][lane][dt * 4 + r] * aB) * inv);
                // O^T[d][q]: lane writes 4 consecutive d at row t=qg
                *reinterpret_cast<ushort4*>(&ctx[(size_t)qg * Q_SZ + h * HEAD_DIM + dt * 16 + quad * 4]) =
                    *reinterpret_cast<const ushort4*>(o);
            }
        }
        __syncthreads();   // smO/smML reused next pass
    }
}

extern "C" void kernel_launch(void* const* d_in, const int* in_sizes, int n_in,
                              void* d_out, int out_size, void* d_ws, size_t ws_size,
                              hipStream_t stream) {
    (void)in_sizes; (void)n_in; (void)out_size; (void)ws_size;
    const int*   positions = (const int*)d_in[0];
    const float* hidden    = (const float*)d_in[1];
    const float* w_qkv     = (const float*)d_in[2];
    const float* b_qkv     = (const float*)d_in[3];
    const float* w_dense   = (const float*)d_in[4];
    float* out = (float*)d_out;

    char* ws = (char*)d_ws;
    __hip_bfloat16* h_bf   = (__hip_bfloat16*)ws; ws += (size_t)T_SEQ * HIDDEN_SZ * 2;
    __hip_bfloat16* wqkvT  = (__hip_bfloat16*)ws; ws += (size_t)QKV_DIM * HIDDEN_SZ * 2;
    __hip_bfloat16* wdT    = (__hip_bfloat16*)ws; ws += (size_t)HIDDEN_SZ * HIDDEN_SZ * 2;
    __hip_bfloat16* qkv_bf = (__hip_bfloat16*)ws; ws += (size_t)T_SEQ * QKV_DIM * 2;
    __hip_bfloat16* q_bf   = (__hip_bfloat16*)ws; ws += (size_t)NUM_HEADS * T_SEQ * HEAD_DIM * 2;
    __hip_bfloat16* k_bf   = (__hip_bfloat16*)ws; ws += (size_t)KV_GROUPS * T_SEQ * HEAD_DIM * 2;
    __hip_bfloat16* vT_bf  = (__hip_bfloat16*)ws; ws += (size_t)KV_GROUPS * HEAD_DIM * T_SEQ * 2;
    __hip_bfloat16* ctx_bf = h_bf;  // h_bf dead after QKV GEMM; reuse for ctx

    // 1) hidden fp32 -> bf16
    convert_bf16_kernel<<<(T_SEQ * HIDDEN_SZ) / (256 * 4), 256, 0, stream>>>(hidden, h_bf, T_SEQ * HIDDEN_SZ);
    // 2) weights fp32 [K][N] -> bf16 [N][K]
    transpose_convert_kernel<<<dim3(QKV_DIM / 64, HIDDEN_SZ / 64), 256, 0, stream>>>(w_qkv, wqkvT, HIDDEN_SZ, QKV_DIM);
    transpose_convert_kernel<<<dim3(HIDDEN_SZ / 64, HIDDEN_SZ / 64), 256, 0, stream>>>(w_dense, wdT, HIDDEN_SZ, HIDDEN_SZ);
    // 3) QKV GEMM (+bias) -> bf16 qkv
    gemm_bf16_kernel<__hip_bfloat16><<<dim3(QKV_DIM / 128, T_SEQ / 128), 256, 0, stream>>>(
        h_bf, wqkvT, b_qkv, qkv_bf, T_SEQ, QKV_DIM, HIDDEN_SZ);
    // 4) RoPE + relayout: Q row-major (pre-scaled), K/V frag-major for coalesced flash loads
    rope_reorg_kernel<<<dim3(T_SEQ, NUM_HEADS + 2 * KV_GROUPS), 64, 0, stream>>>(
        qkv_bf, positions, q_bf, k_bf, vT_bf);
    // 5) causal GQA flash attention (split-K, frag-major K/V) -> ctx bf16 [t][h*128+d]
    flash_attn_kernel<<<dim3(32, NUM_HEADS), 256, 0, stream>>>(q_bf, k_bf, vT_bf, ctx_bf);
    // 6) dense GEMM -> fp32 out
    gemm_bf16_kernel<float><<<dim3(HIDDEN_SZ / 128, T_SEQ / 128), 256, 0, stream>>>(
        ctx_bf, wdT, nullptr, out, T_SEQ, HIDDEN_SZ, HIDDEN_SZ);
}

// Round 4
// 514.726 us; speedup vs baseline: 1.4692x; 1.0423x over previous
//
#include <hip/hip_runtime.h>
#include <hip/hip_bf16.h>

#define T_SEQ 2048
#define HIDDEN_SZ 4096
#define NUM_HEADS 32
#define HEAD_DIM 128
#define KV_GROUPS 2
#define Q_SZ 4096          // NUM_HEADS*HEAD_DIM
#define KV_SZ 256          // KV_GROUPS*HEAD_DIM
#define QKV_DIM 4608       // Q_SZ + 2*KV_SZ

typedef __attribute__((ext_vector_type(8))) short bf16x8_t;   // 8 bf16 = 4 VGPR (A/B frag)
typedef __attribute__((ext_vector_type(4))) float f32x4_t;    // C/D frag

__device__ inline void store_c(float* p, float v) { *p = v; }
__device__ inline void store_c(__hip_bfloat16* p, float v) { *p = __float2bfloat16(v); }

// async global->LDS, 16B per lane; LDS dest = wave-uniform base + lane*16
#define GLDS16(gp, lp)                                                                  \
    __builtin_amdgcn_global_load_lds((const __attribute__((address_space(1))) unsigned int*)(gp), \
                                     (__attribute__((address_space(3))) unsigned int*)(lp), 16, 0, 0)

// ---------------- fp32 -> bf16 contiguous convert ----------------
__global__ __launch_bounds__(256) void convert_bf16_kernel(const float* __restrict__ in,
                                                           __hip_bfloat16* __restrict__ out,
                                                           int n) {
    int i = (blockIdx.x * 256 + threadIdx.x) * 4;
    if (i + 3 < n) {
        float4 v = *reinterpret_cast<const float4*>(in + i);
        alignas(8) __hip_bfloat16 tmp[4] = {__float2bfloat16(v.x), __float2bfloat16(v.y),
                                            __float2bfloat16(v.z), __float2bfloat16(v.w)};
        *reinterpret_cast<ushort4*>(out + i) = *reinterpret_cast<const ushort4*>(tmp);
    }
}

// ---------------- fp32 [R][C] -> bf16 [C][R] tile transpose (64x64, vectorized) ----------------
__global__ __launch_bounds__(256) void transpose_convert_kernel(const float* __restrict__ in,
                                                                __hip_bfloat16* __restrict__ out,
                                                                int R, int C) {
    __shared__ float tile[64][65];   // pad 65: column reads conflict-free
    const int tx = threadIdx.x & 15;   // 0..15
    const int ty = threadIdx.x >> 4;   // 0..15
    const int c0 = blockIdx.x * 64, r0 = blockIdx.y * 64;
    #pragma unroll
    for (int i = 0; i < 4; ++i) {
        int row = ty + 16 * i;
        float4 v = *reinterpret_cast<const float4*>(&in[(size_t)(r0 + row) * C + c0 + tx * 4]);
        tile[row][tx * 4 + 0] = v.x; tile[row][tx * 4 + 1] = v.y;
        tile[row][tx * 4 + 2] = v.z; tile[row][tx * 4 + 3] = v.w;
    }
    __syncthreads();
    #pragma unroll
    for (int i = 0; i < 4; ++i) {
        int ocol = ty + 16 * i;
        alignas(8) __hip_bfloat16 o[4];
        #pragma unroll
        for (int j = 0; j < 4; ++j) o[j] = __float2bfloat16(tile[tx * 4 + j][ocol]);
        *reinterpret_cast<ushort4*>(&out[(size_t)(c0 + ocol) * R + r0 + tx * 4]) =
            *reinterpret_cast<const ushort4*>(o);
    }
}

// ---------------- bf16 MFMA GEMM: C[M][N] = A[M][K] * BT[N][K]^T (+bias) ----------------
// 128x128 block tile, 4 waves (2x2), each wave 64x64 = 4x4 accums of 16x16, BK=32.
// Round-4 changes vs the verified m97-style serial loop (which measured MfmaUtil 22%,
// occupancy grid-capped at 2.25 blocks/CU -> no TLP to hide the stage drain):
//  (a) 2-phase double-buffered pipeline (T3-minimum): STAGE(t+1) into buf^1 is issued
//      BEFORE computing buf t; counted `s_waitcnt vmcnt(4)` keeps the 4 prefetch
//      global_load_lds in flight across the barrier; raw s_barrier (NOT __syncthreads,
//      which forces a vmcnt(0) drain); sched_barrier(0) pins ds_reads/MFMA against
//      hoisting/sinking across the barriers (rule-#18 hazard).
//  (b) bijective XCD swizzle on the linear block id (nwg % 8 == 0 for both call sites):
//      each XCD gets a contiguous work range -> A-panel reuse in its private L2.
template <typename OutT>
__global__ __launch_bounds__(256) void gemm_bf16_kernel(const __hip_bfloat16* __restrict__ A,
                                                        const __hip_bfloat16* __restrict__ BT,
                                                        const float* __restrict__ bias,
                                                        OutT* __restrict__ C,
                                                        int M, int N, int K) {
    constexpr int BM = 128, BN = 128, BK = 32;
    __shared__ __hip_bfloat16 lA[2][BM * BK];   // double-buffered, packed row*32+col
    __shared__ __hip_bfloat16 lB[2][BN * BK];
    const int tid = threadIdx.x;
    // XCD swizzle: work id = (bid%8)*(nwg/8) + bid/8  (bijective when nwg%8==0)
    const int nwg = gridDim.x * gridDim.y;
    const int bid = blockIdx.y * gridDim.x + blockIdx.x;
    const int swz = (bid & 7) * (nwg >> 3) + (bid >> 3);
    const int bm = (swz / gridDim.x) * BM, bn = (swz % gridDim.x) * BN;
    const int wave = tid >> 6, lane = tid & 63;
    const int wr = wave >> 1, wc = wave & 1;
    const int n16 = lane & 15, quad = lane >> 4;
    const int lrow = lane >> 2;          // 0..15 within a 16-row chunk
    const int lcol = (lane & 3) * 8;     // elem col 0,8,16,24
    f32x4_t acc[4][4] = {};

    // stage tile t into LDS buffer `buf`: 4 GLDS per wave (2 A-chunks + 2 B-chunks)
    auto STAGE = [&](int buf, int t) {
        const int kk = t * BK;
        #pragma unroll
        for (int p = 0; p < 2; ++p) {
            int ca = wave * 2 + p;                 // chunk 0..7
            int row = ca * 16 + lrow;
            GLDS16(&A[(size_t)(bm + row) * K + kk + lcol], &lA[buf][ca * 512]);
            GLDS16(&BT[(size_t)(bn + row) * K + kk + lcol], &lB[buf][ca * 512]);
        }
    };
    auto COMPUTE = [&](int buf) {
        bf16x8_t af[4], bfr[4];
        #pragma unroll
        for (int i = 0; i < 4; ++i)
            af[i] = *reinterpret_cast<const bf16x8_t*>(&lA[buf][(wr * 64 + i * 16 + n16) * BK + quad * 8]);
        #pragma unroll
        for (int j = 0; j < 4; ++j)
            bfr[j] = *reinterpret_cast<const bf16x8_t*>(&lB[buf][(wc * 64 + j * 16 + n16) * BK + quad * 8]);
        #pragma unroll
        for (int i = 0; i < 4; ++i)
            #pragma unroll
            for (int j = 0; j < 4; ++j)
                acc[i][j] = __builtin_amdgcn_mfma_f32_16x16x32_bf16(af[i], bfr[j], acc[i][j], 0, 0, 0);
    };

    const int nt = K / BK;
    STAGE(0, 0);                                   // prologue
    for (int t = 0; t < nt - 1; ++t) {
        STAGE((t + 1) & 1, t + 1);                 // prefetch next tile (stays in flight)
        asm volatile("s_waitcnt vmcnt(4)" ::: "memory");   // current tile's 4 loads done
        __builtin_amdgcn_s_barrier();              // all waves' current-tile chunks in LDS
        __builtin_amdgcn_sched_barrier(0);         // no ds_read hoist above barrier
        COMPUTE(t & 1);
        __builtin_amdgcn_sched_barrier(0);         // no MFMA/ds_read sink below barrier
        __builtin_amdgcn_s_barrier();              // buf (t&1) free for overwrite at t+2
    }
    asm volatile("s_waitcnt vmcnt(0)" ::: "memory");       // drain last stage
    __builtin_amdgcn_s_barrier();
    __builtin_amdgcn_sched_barrier(0);
    COMPUTE((nt - 1) & 1);

    #pragma unroll
    for (int i = 0; i < 4; ++i) {
        #pragma unroll
        for (int j = 0; j < 4; ++j) {
            int col = bn + wc * 64 + j * 16 + n16;
            float bv = bias ? bias[col] : 0.0f;
            #pragma unroll
            for (int r = 0; r < 4; ++r) {
                int row = bm + wr * 64 + i * 16 + quad * 4 + r;   // C/D: col=lane&15, row=quad*4+reg
                store_c(&C[(size_t)row * N + col], acc[i][j][r] + bv);
            }
        }
    }
}

// ---------------- RoPE + relayout ----------------
// qkv[t][4608] -> q[h][t][d]  (row-major, as before)
//                 kfrag[g][kt][c][f][lane][8]  (frag-major: flash kf loads are contiguous)
//                 vfrag[g][kt][dt][lane][8]    (frag-major: flash vf loads are contiguous)
// Frag-major inverts the flash fragment mapping (round-2 verified formulas):
//   K: lane(n16,quad) elem j of kf[c][f] = K[kt*32 + (n16>>2)*8 + c*4 + (n16&3)][f*32+quad*8+j]
//   V: lane(n16,quad) elem j of vf[dt]   = V[kt*32 + quad*8 + j][dt*16 + n16]
// Q is pre-scaled by (1/sqrt(128))*log2(e) so flash attention can use raw exp2.
__global__ __launch_bounds__(64) void rope_reorg_kernel(const __hip_bfloat16* __restrict__ qkv,
                                                        const int* __restrict__ positions,
                                                        __hip_bfloat16* __restrict__ qo,
                                                        __hip_bfloat16* __restrict__ ko,
                                                        __hip_bfloat16* __restrict__ vTo) {
    const int t = blockIdx.x;
    const int u = blockIdx.y;       // 0..31 q heads, 32..33 k groups, 34..35 v groups
    const int tid = threadIdx.x;    // 0..63, handles dims (2*tid, 2*tid+1)
    const int d0 = tid * 2, d1 = d0 + 1;
    int col;
    if (u < 32) col = u * HEAD_DIM;
    else if (u < 34) col = Q_SZ + (u - 32) * HEAD_DIM;
    else col = Q_SZ + KV_SZ + (u - 34) * HEAD_DIM;
    float x0 = __bfloat162float(qkv[(size_t)t * QKV_DIM + col + d0]);
    float x1 = __bfloat162float(qkv[(size_t)t * QKV_DIM + col + d1]);
    float o0 = x0, o1 = x1;
    if (u < 34 && tid < 32) {  // rot_dim = 64: pairs i=0..31; dims 64..127 pass through
        float pos = (float)positions[t];
        float theta = exp2f(-(float)tid * 0.4152410118609203f);  // 10000^(-i/32)
        float ang = pos * theta;
        float sn, cs;
        sincosf(ang, &sn, &cs);
        o0 = x0 * cs - x1 * sn;
        o1 = x1 * cs + x0 * sn;
    }
    if (u < 32) {
        constexpr float qscale = 0.08838834764831845f * 1.4426950408889634f;  // rsqrt(128)*log2e
        __hip_bfloat16* dst = qo + ((size_t)u * T_SEQ + t) * HEAD_DIM;
        dst[d0] = __float2bfloat16(o0 * qscale);
        dst[d1] = __float2bfloat16(o1 * qscale);
    } else if (u < 34) {
        // K frag-major. key t: kt=t>>5, kw=t&31 -> c=(kw>>2)&1, n16=((kw>>3)<<2)|(kw&3)
        // dim d0 (even): f=d0>>5, quad=(d0>>3)&3, j0=d0&7 (d1 = same frag, j0+1)
        const int gg = u - 32;
        const int kt = t >> 5, kw = t & 31;
        const int c = (kw >> 2) & 1;
        const int n16k = ((kw >> 3) << 2) | (kw & 3);
        const int f = d0 >> 5, quad = (d0 >> 3) & 3, j0 = d0 & 7;
        __hip_bfloat16* dst = ko + (size_t)gg * (T_SEQ * HEAD_DIM) +
                              ((size_t)(((kt * 2 + c) * 4 + f)) << 9) + (quad * 16 + n16k) * 8 + j0;
        dst[0] = __float2bfloat16(o0);
        dst[1] = __float2bfloat16(o1);
    } else {
        // V frag-major. key t: kt=t>>5, kw=t&31 -> quad=kw>>3, j=kw&7
        // dim d0 (even): dt=d0>>4, n16=d0&15 (d1 -> n16+1, idx+8)
        const int gg = u - 34;
        const int kt = t >> 5, kw = t & 31;
        const int quad = kw >> 3, j = kw & 7;
        const int dt0 = d0 >> 4, n0 = d0 & 15;
        __hip_bfloat16* dst = vTo + (size_t)gg * (T_SEQ * HEAD_DIM) +
                              ((size_t)(kt * 8 + dt0) << 9) + (quad * 16 + n0) * 8 + j;
        dst[0] = __float2bfloat16(o0);
        dst[8] = __float2bfloat16(o1);
    }
}

// ---------------- causal GQA flash attention (frag-major K/V, split-K balanced) ----------------
// S^T = K*Q^T with key-row permutation so S C-regs concatenate into the PV B-frag.
// Frag-major K/V (round 3, verified): each kf/vf load reads 64 lanes x 16B = 1KB
// contiguous; flash dropped 251.6 -> ~96 µs.
// Split-K (flash-decoding): chunk pair (p,127-p) split across two waves by key range,
// merged in-block via LDS online-softmax algebra; every wave ~32-33 tiles, exact
// balance, no dispatch-mapping assumptions. No min-waves launch bound (round-1 spill).
__global__ __launch_bounds__(256) void flash_attn_kernel(const __hip_bfloat16* __restrict__ q,
                                                         const __hip_bfloat16* __restrict__ k,
                                                         const __hip_bfloat16* __restrict__ vT,
                                                         __hip_bfloat16* __restrict__ ctx) {
    const int h = blockIdx.y;           // 0..31
    const int g = h >> 4;               // kv group
    const int wave = threadIdx.x >> 6;
    const int lane = threadIdx.x & 63;
    const int n16 = lane & 15, quad = lane >> 4;
    const int wid = blockIdx.x * 4 + wave;   // 0..127
    const int pr = wid >> 1;                 // pair id 0..63
    const int half = wid & 1;                // 0 = early keys, 1 = late keys (incl. diagonal)
    const int pslot = wave >> 1;             // pair slot within block: 0..1
    const __hip_bfloat16* kbase = k + (size_t)g * (T_SEQ * HEAD_DIM) + (size_t)lane * 8;
    const __hip_bfloat16* vbase = vT + (size_t)g * (T_SEQ * HEAD_DIM) + (size_t)lane * 8;

    // merge buffers: stride 33 floats -> bank = (lane + j) % 32, conflict-free
    __shared__ float smO[2][64][33];
    __shared__ float smML[2][64][2];

    for (int pass = 0; pass < 2; ++pass) {
        const int chunk = pass ? (127 - pr) : pr;    // paired light+heavy: 65-66 tiles/pair
        const int qrow0 = chunk * 16;
        const int nt = (chunk >> 1) + 1;             // key tiles for this chunk
        const int ktA = half ? (nt >> 1) : 0;        // this wave's [ktA, ktB) tile range
        const int ktB = half ? nt : (nt >> 1);
        const int qg = qrow0 + n16;

        // Q B-frags: B[n=q(n16)][k=d(quad*8+j)], 4 frags over d=128
        const __hip_bfloat16* qrow = q + ((size_t)h * T_SEQ + qg) * HEAD_DIM;
        bf16x8_t qf[4];
        #pragma unroll
        for (int f = 0; f < 4; ++f)
            qf[f] = *reinterpret_cast<const bf16x8_t*>(qrow + f * 32 + quad * 8);

        f32x4_t accO[8] = {};
        float m_ = -1e30f, l_ = 0.0f;

        if (ktA < ktB) {
            bf16x8_t kf[2][4];
            #pragma unroll
            for (int c = 0; c < 2; ++c)
                #pragma unroll
                for (int f = 0; f < 4; ++f)
                    kf[c][f] = *reinterpret_cast<const bf16x8_t*>(
                        kbase + ((size_t)((ktA * 2 + c) * 4 + f) << 9));

            for (int kt = ktA; kt < ktB; ++kt) {
                // QK^T (transposed): s[c] rows = keys quad*8+c*4+r, cols = q
                f32x4_t s[2] = {};
                #pragma unroll
                for (int c = 0; c < 2; ++c)
                    #pragma unroll
                    for (int f = 0; f < 4; ++f)
                        s[c] = __builtin_amdgcn_mfma_f32_16x16x32_bf16(kf[c][f], qf[f], s[c], 0, 0, 0);
                // prefetch next K tile (WAR on kf orders these after the MFMAs)
                if (kt + 1 < ktB) {
                    int ktn = kt + 1;
                    #pragma unroll
                    for (int c = 0; c < 2; ++c)
                        #pragma unroll
                        for (int f = 0; f < 4; ++f)
                            kf[c][f] = *reinterpret_cast<const bf16x8_t*>(
                                kbase + ((size_t)((ktn * 2 + c) * 4 + f) << 9));
                }
                // V A-frags: A[m=d(n16)][k=key(quad*8+j)] — issued early, consumed after softmax
                bf16x8_t vf[8];
                #pragma unroll
                for (int dt = 0; dt < 8; ++dt)
                    vf[dt] = *reinterpret_cast<const bf16x8_t*>(
                        vbase + ((size_t)(kt * 8 + dt) << 9));

                // causal mask (only tiles crossing the diagonal)
                if (kt * 32 + 31 > qrow0) {
                    #pragma unroll
                    for (int c = 0; c < 2; ++c)
                        #pragma unroll
                        for (int r = 0; r < 4; ++r)
                            if (kt * 32 + quad * 8 + c * 4 + r > qg) s[c][r] = -1e30f;
                }
                // per-lane max over this lane's 8 keys, then 2 shuffles across quads
                float xm = fmaxf(fmaxf(fmaxf(s[0][0], s[0][1]), fmaxf(s[0][2], s[0][3])),
                                 fmaxf(fmaxf(s[1][0], s[1][1]), fmaxf(s[1][2], s[1][3])));
                xm = fmaxf(xm, __shfl_xor(xm, 16, 64));
                xm = fmaxf(xm, __shfl_xor(xm, 32, 64));
                float mn = fmaxf(m_, xm);
                float alpha = __builtin_amdgcn_exp2f(m_ - mn);
                m_ = mn;
                float p[2][4];
                #pragma unroll
                for (int c = 0; c < 2; ++c)
                    #pragma unroll
                    for (int r = 0; r < 4; ++r)
                        p[c][r] = __builtin_amdgcn_exp2f(s[c][r] - mn);
                // pack P^T into the K=32 B-frag: j=0..3 -> tile0, j=4..7 -> tile1
                union { bf16x8_t v; __hip_bfloat16 e[8]; } pf;
                #pragma unroll
                for (int c = 0; c < 2; ++c)
                    #pragma unroll
                    for (int r = 0; r < 4; ++r)
                        pf.e[c * 4 + r] = __float2bfloat16(p[c][r]);
                // rescale O^T by per-lane scalar alpha (skip when no lane's max moved)
                if (__any(alpha < 1.0f)) {
                    #pragma unroll
                    for (int dt = 0; dt < 8; ++dt)
                        #pragma unroll
                        for (int r = 0; r < 4; ++r) accO[dt][r] *= alpha;
                }
                // PV: O^T[d][q] += V^T[d][key] * P^T[key][q]
                #pragma unroll
                for (int dt = 0; dt < 8; ++dt)
                    accO[dt] = __builtin_amdgcn_mfma_f32_16x16x32_bf16(vf[dt], pf.v, accO[dt], 0, 0, 0);
                // l update (independent of PV; scheduler overlaps)
                float xs = ((p[0][0] + p[0][1]) + (p[0][2] + p[0][3])) +
                           ((p[1][0] + p[1][1]) + (p[1][2] + p[1][3]));
                xs += __shfl_xor(xs, 16, 64);
                xs += __shfl_xor(xs, 32, 64);
                l_ = l_ * alpha + xs;
            }
        }

        // ---- merge the two key-halves of this pair through LDS ----
        if (half) {
            #pragma unroll
            for (int dt = 0; dt < 8; ++dt)
                #pragma unroll
                for (int r = 0; r < 4; ++r) smO[pslot][lane][dt * 4 + r] = accO[dt][r];
            smML[pslot][lane][0] = m_;
            smML[pslot][lane][1] = l_;
        }
        __syncthreads();
        if (!half) {
            // half=1 always has >=1 tile (it owns the diagonal) -> mB finite, lB > 0.
            // half=0 may be empty (nt==1): m_=-1e30 -> aA underflows to exactly 0.
            float mB = smML[pslot][lane][0], lB = smML[pslot][lane][1];
            float mN = fmaxf(m_, mB);
            float aA = __builtin_amdgcn_exp2f(m_ - mN);
            float aB = __builtin_amdgcn_exp2f(mB - mN);
            float inv = 1.0f / (l_ * aA + lB * aB);
            #pragma unroll
            for (int dt = 0; dt < 8; ++dt) {
                alignas(8) __hip_bfloat16 o[4];
                #pragma unroll
                for (int r = 0; r < 4; ++r)
                    o[r] = __float2bfloat16((accO[dt][r] * aA + smO[pslot][lane][dt * 4 + r] * aB) * inv);
                // O^T[d][q]: lane writes 4 consecutive d at row t=qg
                *reinterpret_cast<ushort4*>(&ctx[(size_t)qg * Q_SZ + h * HEAD_DIM + dt * 16 + quad * 4]) =
                    *reinterpret_cast<const ushort4*>(o);
            }
        }
        __syncthreads();   // smO/smML reused next pass
    }
}

extern "C" void kernel_launch(void* const* d_in, const int* in_sizes, int n_in,
                              void* d_out, int out_size, void* d_ws, size_t ws_size,
                              hipStream_t stream) {
    (void)in_sizes; (void)n_in; (void)out_size; (void)ws_size;
    const int*   positions = (const int*)d_in[0];
    const float* hidden    = (const float*)d_in[1];
    const float* w_qkv     = (const float*)d_in[2];
    const float* b_qkv     = (const float*)d_in[3];
    const float* w_dense   = (const float*)d_in[4];
    float* out = (float*)d_out;

    char* ws = (char*)d_ws;
    __hip_bfloat16* h_bf   = (__hip_bfloat16*)ws; ws += (size_t)T_SEQ * HIDDEN_SZ * 2;
    __hip_bfloat16* wqkvT  = (__hip_bfloat16*)ws; ws += (size_t)QKV_DIM * HIDDEN_SZ * 2;
    __hip_bfloat16* wdT    = (__hip_bfloat16*)ws; ws += (size_t)HIDDEN_SZ * HIDDEN_SZ * 2;
    __hip_bfloat16* qkv_bf = (__hip_bfloat16*)ws; ws += (size_t)T_SEQ * QKV_DIM * 2;
    __hip_bfloat16* q_bf   = (__hip_bfloat16*)ws; ws += (size_t)NUM_HEADS * T_SEQ * HEAD_DIM * 2;
    __hip_bfloat16* k_bf   = (__hip_bfloat16*)ws; ws += (size_t)KV_GROUPS * T_SEQ * HEAD_DIM * 2;
    __hip_bfloat16* vT_bf  = (__hip_bfloat16*)ws; ws += (size_t)KV_GROUPS * HEAD_DIM * T_SEQ * 2;
    __hip_bfloat16* ctx_bf = h_bf;  // h_bf dead after QKV GEMM; reuse for ctx

    // 1) hidden fp32 -> bf16
    convert_bf16_kernel<<<(T_SEQ * HIDDEN_SZ) / (256 * 4), 256, 0, stream>>>(hidden, h_bf, T_SEQ * HIDDEN_SZ);
    // 2) weights fp32 [K][N] -> bf16 [N][K]
    transpose_convert_kernel<<<dim3(QKV_DIM / 64, HIDDEN_SZ / 64), 256, 0, stream>>>(w_qkv, wqkvT, HIDDEN_SZ, QKV_DIM);
    transpose_convert_kernel<<<dim3(HIDDEN_SZ / 64, HIDDEN_SZ / 64), 256, 0, stream>>>(w_dense, wdT, HIDDEN_SZ, HIDDEN_SZ);
    // 3) QKV GEMM (+bias) -> bf16 qkv   (grid 36*16=576 blocks, %8==0 for XCD swizzle)
    gemm_bf16_kernel<__hip_bfloat16><<<dim3(QKV_DIM / 128, T_SEQ / 128), 256, 0, stream>>>(
        h_bf, wqkvT, b_qkv, qkv_bf, T_SEQ, QKV_DIM, HIDDEN_SZ);
    // 4) RoPE + relayout: Q row-major (pre-scaled), K/V frag-major for coalesced flash loads
    rope_reorg_kernel<<<dim3(T_SEQ, NUM_HEADS + 2 * KV_GROUPS), 64, 0, stream>>>(
        qkv_bf, positions, q_bf, k_bf, vT_bf);
    // 5) causal GQA flash attention (split-K, frag-major K/V) -> ctx bf16 [t][h*128+d]
    flash_attn_kernel<<<dim3(32, NUM_HEADS), 256, 0, stream>>>(q_bf, k_bf, vT_bf, ctx_bf);
    // 6) dense GEMM -> fp32 out   (grid 32*16=512 blocks, %8==0 for XCD swizzle)
    gemm_bf16_kernel<float><<<dim3(HIDDEN_SZ / 128, T_SEQ / 128), 256, 0, stream>>>(
        ctx_bf, wdT, nullptr, out, T_SEQ, HIDDEN_SZ, HIDDEN_SZ);
}

// Round 5
// 513.655 us; speedup vs baseline: 1.4722x; 1.0021x over previous
//
#include <hip/hip_runtime.h>
#include <hip/hip_bf16.h>

#define T_SEQ 2048
#define HIDDEN_SZ 4096
#define NUM_HEADS 32
#define HEAD_DIM 128
#define KV_GROUPS 2
#define Q_SZ 4096          // NUM_HEADS*HEAD_DIM
#define KV_SZ 256          // KV_GROUPS*HEAD_DIM
#define QKV_DIM 4608       // Q_SZ + 2*KV_SZ

typedef __attribute__((ext_vector_type(8))) short bf16x8_t;   // 8 bf16 = 4 VGPR (A/B frag)
typedef __attribute__((ext_vector_type(4))) float f32x4_t;    // C/D frag

__device__ inline void store_c(float* p, float v) { *p = v; }
__device__ inline void store_c(__hip_bfloat16* p, float v) { *p = __float2bfloat16(v); }

// async global->LDS, 16B per lane; LDS dest = wave-uniform base + lane*16
#define GLDS16(gp, lp)                                                                  \
    __builtin_amdgcn_global_load_lds((const __attribute__((address_space(1))) unsigned int*)(gp), \
                                     (__attribute__((address_space(3))) unsigned int*)(lp), 16, 0, 0)

// ---------------- fp32 -> bf16 contiguous convert ----------------
__global__ __launch_bounds__(256) void convert_bf16_kernel(const float* __restrict__ in,
                                                           __hip_bfloat16* __restrict__ out,
                                                           int n) {
    int i = (blockIdx.x * 256 + threadIdx.x) * 4;
    if (i + 3 < n) {
        float4 v = *reinterpret_cast<const float4*>(in + i);
        alignas(8) __hip_bfloat16 tmp[4] = {__float2bfloat16(v.x), __float2bfloat16(v.y),
                                            __float2bfloat16(v.z), __float2bfloat16(v.w)};
        *reinterpret_cast<ushort4*>(out + i) = *reinterpret_cast<const ushort4*>(tmp);
    }
}

// ---------------- fp32 [R][C] -> bf16 [C][R] tile transpose (64x64, vectorized) ----------------
__global__ __launch_bounds__(256) void transpose_convert_kernel(const float* __restrict__ in,
                                                                __hip_bfloat16* __restrict__ out,
                                                                int R, int C) {
    __shared__ float tile[64][65];   // pad 65: column reads conflict-free
    const int tx = threadIdx.x & 15;   // 0..15
    const int ty = threadIdx.x >> 4;   // 0..15
    const int c0 = blockIdx.x * 64, r0 = blockIdx.y * 64;
    #pragma unroll
    for (int i = 0; i < 4; ++i) {
        int row = ty + 16 * i;
        float4 v = *reinterpret_cast<const float4*>(&in[(size_t)(r0 + row) * C + c0 + tx * 4]);
        tile[row][tx * 4 + 0] = v.x; tile[row][tx * 4 + 1] = v.y;
        tile[row][tx * 4 + 2] = v.z; tile[row][tx * 4 + 3] = v.w;
    }
    __syncthreads();
    #pragma unroll
    for (int i = 0; i < 4; ++i) {
        int ocol = ty + 16 * i;
        alignas(8) __hip_bfloat16 o[4];
        #pragma unroll
        for (int j = 0; j < 4; ++j) o[j] = __float2bfloat16(tile[tx * 4 + j][ocol]);
        *reinterpret_cast<ushort4*>(&out[(size_t)(c0 + ocol) * R + r0 + tx * 4]) =
            *reinterpret_cast<const ushort4*>(o);
    }
}

// ---------------- bf16 MFMA GEMM: C[M][N] = A[M][K] * BT[N][K]^T (+bias) ----------------
// 128x128 block tile, 4 waves (2x2), each wave 64x64 = 4x4 accums of 16x16, BK=32.
// Round-5: 3-buffer pipeline, prefetch distance 2. Round-4's d=1 window (~1 compute
// phase ~300cyc) was shorter than the L3/HBM miss latency (FETCH=3x input footprint),
// so vmcnt(4) stalled every K-step. d=2 gives ~2 phases (~700cyc). Both barriers kept:
// stage(t+3) next epoch overwrites buf t%3 only after barrier-2 confirms COMPUTE(t)
// done by all waves (NB=3 >= d+2 hazard rule). LDS 48KB -> still 3 blocks/CU co-res.
// vmcnt(8) = 8 outstanding (tiles t+1,t+2) -> tile t's 4 loads complete (FIFO).
// XCD swizzle: bijective when nwg%8==0 (both call sites comply).
template <typename OutT>
__global__ __launch_bounds__(256) void gemm_bf16_kernel(const __hip_bfloat16* __restrict__ A,
                                                        const __hip_bfloat16* __restrict__ BT,
                                                        const float* __restrict__ bias,
                                                        OutT* __restrict__ C,
                                                        int M, int N, int K) {
    constexpr int BM = 128, BN = 128, BK = 32;
    __shared__ __hip_bfloat16 lA[3][BM * BK];   // triple-buffered, packed row*32+col
    __shared__ __hip_bfloat16 lB[3][BN * BK];
    const int tid = threadIdx.x;
    // XCD swizzle: work id = (bid%8)*(nwg/8) + bid/8  (bijective when nwg%8==0)
    const int nwg = gridDim.x * gridDim.y;
    const int bid = blockIdx.y * gridDim.x + blockIdx.x;
    const int swz = (bid & 7) * (nwg >> 3) + (bid >> 3);
    const int bm = (swz / gridDim.x) * BM, bn = (swz % gridDim.x) * BN;
    const int wave = tid >> 6, lane = tid & 63;
    const int wr = wave >> 1, wc = wave & 1;
    const int n16 = lane & 15, quad = lane >> 4;
    const int lrow = lane >> 2;          // 0..15 within a 16-row chunk
    const int lcol = (lane & 3) * 8;     // elem col 0,8,16,24
    f32x4_t acc[4][4] = {};

    // stage tile t into LDS buffer `buf`: 4 GLDS per wave (2 A-chunks + 2 B-chunks)
    auto STAGE = [&](int buf, int t) {
        const int kk = t * BK;
        #pragma unroll
        for (int p = 0; p < 2; ++p) {
            int ca = wave * 2 + p;                 // chunk 0..7
            int row = ca * 16 + lrow;
            GLDS16(&A[(size_t)(bm + row) * K + kk + lcol], &lA[buf][ca * 512]);
            GLDS16(&BT[(size_t)(bn + row) * K + kk + lcol], &lB[buf][ca * 512]);
        }
    };
    auto COMPUTE = [&](int buf) {
        bf16x8_t af[4], bfr[4];
        #pragma unroll
        for (int i = 0; i < 4; ++i)
            af[i] = *reinterpret_cast<const bf16x8_t*>(&lA[buf][(wr * 64 + i * 16 + n16) * BK + quad * 8]);
        #pragma unroll
        for (int j = 0; j < 4; ++j)
            bfr[j] = *reinterpret_cast<const bf16x8_t*>(&lB[buf][(wc * 64 + j * 16 + n16) * BK + quad * 8]);
        #pragma unroll
        for (int i = 0; i < 4; ++i)
            #pragma unroll
            for (int j = 0; j < 4; ++j)
                acc[i][j] = __builtin_amdgcn_mfma_f32_16x16x32_bf16(af[i], bfr[j], acc[i][j], 0, 0, 0);
    };

    const int nt = K / BK;                         // 128
    STAGE(0, 0);                                   // prologue: tiles 0,1 in flight
    STAGE(1, 1);
    int cur = 0;
    for (int t = 0; t < nt - 2; ++t) {
        int nxt = cur + 2; if (nxt >= 3) nxt -= 3;
        STAGE(nxt, t + 2);                         // prefetch tile t+2 (12 loads in flight)
        asm volatile("s_waitcnt vmcnt(8)" ::: "memory");   // tile t's 4 loads landed
        __builtin_amdgcn_s_barrier();              // all waves' tile-t chunks in LDS
        __builtin_amdgcn_sched_barrier(0);         // no ds_read hoist above barrier
        COMPUTE(cur);
        __builtin_amdgcn_sched_barrier(0);         // no MFMA/ds_read sink below barrier
        __builtin_amdgcn_s_barrier();              // buf cur free for overwrite
        cur = (cur + 1 == 3) ? 0 : cur + 1;
    }
    // tile nt-2: only tile nt-1's 4 loads may remain outstanding
    asm volatile("s_waitcnt vmcnt(4)" ::: "memory");
    __builtin_amdgcn_s_barrier();
    __builtin_amdgcn_sched_barrier(0);
    COMPUTE(cur);
    __builtin_amdgcn_sched_barrier(0);
    __builtin_amdgcn_s_barrier();
    cur = (cur + 1 == 3) ? 0 : cur + 1;
    // tile nt-1: drain
    asm volatile("s_waitcnt vmcnt(0)" ::: "memory");
    __builtin_amdgcn_s_barrier();
    __builtin_amdgcn_sched_barrier(0);
    COMPUTE(cur);

    #pragma unroll
    for (int i = 0; i < 4; ++i) {
        #pragma unroll
        for (int j = 0; j < 4; ++j) {
            int col = bn + wc * 64 + j * 16 + n16;
            float bv = bias ? bias[col] : 0.0f;
            #pragma unroll
            for (int r = 0; r < 4; ++r) {
                int row = bm + wr * 64 + i * 16 + quad * 4 + r;   // C/D: col=lane&15, row=quad*4+reg
                store_c(&C[(size_t)row * N + col], acc[i][j][r] + bv);
            }
        }
    }
}

// ---------------- RoPE + relayout ----------------
// qkv[t][4608] -> q[h][t][d]  (row-major, as before)
//                 kfrag[g][kt][c][f][lane][8]  (frag-major: flash kf loads are contiguous)
//                 vfrag[g][kt][dt][lane][8]    (frag-major: flash vf loads are contiguous)
// Frag-major inverts the flash fragment mapping (round-2 verified formulas):
//   K: lane(n16,quad) elem j of kf[c][f] = K[kt*32 + (n16>>2)*8 + c*4 + (n16&3)][f*32+quad*8+j]
//   V: lane(n16,quad) elem j of vf[dt]   = V[kt*32 + quad*8 + j][dt*16 + n16]
// Q is pre-scaled by (1/sqrt(128))*log2(e) so flash attention can use raw exp2.
__global__ __launch_bounds__(64) void rope_reorg_kernel(const __hip_bfloat16* __restrict__ qkv,
                                                        const int* __restrict__ positions,
                                                        __hip_bfloat16* __restrict__ qo,
                                                        __hip_bfloat16* __restrict__ ko,
                                                        __hip_bfloat16* __restrict__ vTo) {
    const int t = blockIdx.x;
    const int u = blockIdx.y;       // 0..31 q heads, 32..33 k groups, 34..35 v groups
    const int tid = threadIdx.x;    // 0..63, handles dims (2*tid, 2*tid+1)
    const int d0 = tid * 2, d1 = d0 + 1;
    int col;
    if (u < 32) col = u * HEAD_DIM;
    else if (u < 34) col = Q_SZ + (u - 32) * HEAD_DIM;
    else col = Q_SZ + KV_SZ + (u - 34) * HEAD_DIM;
    float x0 = __bfloat162float(qkv[(size_t)t * QKV_DIM + col + d0]);
    float x1 = __bfloat162float(qkv[(size_t)t * QKV_DIM + col + d1]);
    float o0 = x0, o1 = x1;
    if (u < 34 && tid < 32) {  // rot_dim = 64: pairs i=0..31; dims 64..127 pass through
        float pos = (float)positions[t];
        float theta = exp2f(-(float)tid * 0.4152410118609203f);  // 10000^(-i/32)
        float ang = pos * theta;
        float sn, cs;
        sincosf(ang, &sn, &cs);
        o0 = x0 * cs - x1 * sn;
        o1 = x1 * cs + x0 * sn;
    }
    if (u < 32) {
        constexpr float qscale = 0.08838834764831845f * 1.4426950408889634f;  // rsqrt(128)*log2e
        __hip_bfloat16* dst = qo + ((size_t)u * T_SEQ + t) * HEAD_DIM;
        dst[d0] = __float2bfloat16(o0 * qscale);
        dst[d1] = __float2bfloat16(o1 * qscale);
    } else if (u < 34) {
        // K frag-major. key t: kt=t>>5, kw=t&31 -> c=(kw>>2)&1, n16=((kw>>3)<<2)|(kw&3)
        // dim d0 (even): f=d0>>5, quad=(d0>>3)&3, j0=d0&7 (d1 = same frag, j0+1)
        const int gg = u - 32;
        const int kt = t >> 5, kw = t & 31;
        const int c = (kw >> 2) & 1;
        const int n16k = ((kw >> 3) << 2) | (kw & 3);
        const int f = d0 >> 5, quad = (d0 >> 3) & 3, j0 = d0 & 7;
        __hip_bfloat16* dst = ko + (size_t)gg * (T_SEQ * HEAD_DIM) +
                              ((size_t)(((kt * 2 + c) * 4 + f)) << 9) + (quad * 16 + n16k) * 8 + j0;
        dst[0] = __float2bfloat16(o0);
        dst[1] = __float2bfloat16(o1);
    } else {
        // V frag-major. key t: kt=t>>5, kw=t&31 -> quad=kw>>3, j=kw&7
        // dim d0 (even): dt=d0>>4, n16=d0&15 (d1 -> n16+1, idx+8)
        const int gg = u - 34;
        const int kt = t >> 5, kw = t & 31;
        const int quad = kw >> 3, j = kw & 7;
        const int dt0 = d0 >> 4, n0 = d0 & 15;
        __hip_bfloat16* dst = vTo + (size_t)gg * (T_SEQ * HEAD_DIM) +
                              ((size_t)(kt * 8 + dt0) << 9) + (quad * 16 + n0) * 8 + j;
        dst[0] = __float2bfloat16(o0);
        dst[8] = __float2bfloat16(o1);
    }
}

// ---------------- causal GQA flash attention (frag-major K/V, split-K balanced) ----------------
// S^T = K*Q^T with key-row permutation so S C-regs concatenate into the PV B-frag.
// Frag-major K/V (round 3, verified): each kf/vf load reads 64 lanes x 16B = 1KB
// contiguous; flash dropped 251.6 -> ~96 µs.
// Split-K (flash-decoding): chunk pair (p,127-p) split across two waves by key range,
// merged in-block via LDS online-softmax algebra; every wave ~32-33 tiles, exact
// balance, no dispatch-mapping assumptions. No min-waves launch bound (round-1 spill).
__global__ __launch_bounds__(256) void flash_attn_kernel(const __hip_bfloat16* __restrict__ q,
                                                         const __hip_bfloat16* __restrict__ k,
                                                         const __hip_bfloat16* __restrict__ vT,
                                                         __hip_bfloat16* __restrict__ ctx) {
    const int h = blockIdx.y;           // 0..31
    const int g = h >> 4;               // kv group
    const int wave = threadIdx.x >> 6;
    const int lane = threadIdx.x & 63;
    const int n16 = lane & 15, quad = lane >> 4;
    const int wid = blockIdx.x * 4 + wave;   // 0..127
    const int pr = wid >> 1;                 // pair id 0..63
    const int half = wid & 1;                // 0 = early keys, 1 = late keys (incl. diagonal)
    const int pslot = wave >> 1;             // pair slot within block: 0..1
    const __hip_bfloat16* kbase = k + (size_t)g * (T_SEQ * HEAD_DIM) + (size_t)lane * 8;
    const __hip_bfloat16* vbase = vT + (size_t)g * (T_SEQ * HEAD_DIM) + (size_t)lane * 8;

    // merge buffers: stride 33 floats -> bank = (lane + j) % 32, conflict-free
    __shared__ float smO[2][64][33];
    __shared__ float smML[2][64][2];

    for (int pass = 0; pass < 2; ++pass) {
        const int chunk = pass ? (127 - pr) : pr;    // paired light+heavy: 65-66 tiles/pair
        const int qrow0 = chunk * 16;
        const int nt = (chunk >> 1) + 1;             // key tiles for this chunk
        const int ktA = half ? (nt >> 1) : 0;        // this wave's [ktA, ktB) tile range
        const int ktB = half ? nt : (nt >> 1);
        const int qg = qrow0 + n16;

        // Q B-frags: B[n=q(n16)][k=d(quad*8+j)], 4 frags over d=128
        const __hip_bfloat16* qrow = q + ((size_t)h * T_SEQ + qg) * HEAD_DIM;
        bf16x8_t qf[4];
        #pragma unroll
        for (int f = 0; f < 4; ++f)
            qf[f] = *reinterpret_cast<const bf16x8_t*>(qrow + f * 32 + quad * 8);

        f32x4_t accO[8] = {};
        float m_ = -1e30f, l_ = 0.0f;

        if (ktA < ktB) {
            bf16x8_t kf[2][4];
            #pragma unroll
            for (int c = 0; c < 2; ++c)
                #pragma unroll
                for (int f = 0; f < 4; ++f)
                    kf[c][f] = *reinterpret_cast<const bf16x8_t*>(
                        kbase + ((size_t)((ktA * 2 + c) * 4 + f) << 9));

            for (int kt = ktA; kt < ktB; ++kt) {
                // QK^T (transposed): s[c] rows = keys quad*8+c*4+r, cols = q
                f32x4_t s[2] = {};
                #pragma unroll
                for (int c = 0; c < 2; ++c)
                    #pragma unroll
                    for (int f = 0; f < 4; ++f)
                        s[c] = __builtin_amdgcn_mfma_f32_16x16x32_bf16(kf[c][f], qf[f], s[c], 0, 0, 0);
                // prefetch next K tile (WAR on kf orders these after the MFMAs)
                if (kt + 1 < ktB) {
                    int ktn = kt + 1;
                    #pragma unroll
                    for (int c = 0; c < 2; ++c)
                        #pragma unroll
                        for (int f = 0; f < 4; ++f)
                            kf[c][f] = *reinterpret_cast<const bf16x8_t*>(
                                kbase + ((size_t)((ktn * 2 + c) * 4 + f) << 9));
                }
                // V A-frags: A[m=d(n16)][k=key(quad*8+j)] — issued early, consumed after softmax
                bf16x8_t vf[8];
                #pragma unroll
                for (int dt = 0; dt < 8; ++dt)
                    vf[dt] = *reinterpret_cast<const bf16x8_t*>(
                        vbase + ((size_t)(kt * 8 + dt) << 9));

                // causal mask (only tiles crossing the diagonal)
                if (kt * 32 + 31 > qrow0) {
                    #pragma unroll
                    for (int c = 0; c < 2; ++c)
                        #pragma unroll
                        for (int r = 0; r < 4; ++r)
                            if (kt * 32 + quad * 8 + c * 4 + r > qg) s[c][r] = -1e30f;
                }
                // per-lane max over this lane's 8 keys, then 2 shuffles across quads
                float xm = fmaxf(fmaxf(fmaxf(s[0][0], s[0][1]), fmaxf(s[0][2], s[0][3])),
                                 fmaxf(fmaxf(s[1][0], s[1][1]), fmaxf(s[1][2], s[1][3])));
                xm = fmaxf(xm, __shfl_xor(xm, 16, 64));
                xm = fmaxf(xm, __shfl_xor(xm, 32, 64));
                float mn = fmaxf(m_, xm);
                float alpha = __builtin_amdgcn_exp2f(m_ - mn);
                m_ = mn;
                float p[2][4];
                #pragma unroll
                for (int c = 0; c < 2; ++c)
                    #pragma unroll
                    for (int r = 0; r < 4; ++r)
                        p[c][r] = __builtin_amdgcn_exp2f(s[c][r] - mn);
                // pack P^T into the K=32 B-frag: j=0..3 -> tile0, j=4..7 -> tile1
                union { bf16x8_t v; __hip_bfloat16 e[8]; } pf;
                #pragma unroll
                for (int c = 0; c < 2; ++c)
                    #pragma unroll
                    for (int r = 0; r < 4; ++r)
                        pf.e[c * 4 + r] = __float2bfloat16(p[c][r]);
                // rescale O^T by per-lane scalar alpha (skip when no lane's max moved)
                if (__any(alpha < 1.0f)) {
                    #pragma unroll
                    for (int dt = 0; dt < 8; ++dt)
                        #pragma unroll
                        for (int r = 0; r < 4; ++r) accO[dt][r] *= alpha;
                }
                // PV: O^T[d][q] += V^T[d][key] * P^T[key][q]
                #pragma unroll
                for (int dt = 0; dt < 8; ++dt)
                    accO[dt] = __builtin_amdgcn_mfma_f32_16x16x32_bf16(vf[dt], pf.v, accO[dt], 0, 0, 0);
                // l update (independent of PV; scheduler overlaps)
                float xs = ((p[0][0] + p[0][1]) + (p[0][2] + p[0][3])) +
                           ((p[1][0] + p[1][1]) + (p[1][2] + p[1][3]));
                xs += __shfl_xor(xs, 16, 64);
                xs += __shfl_xor(xs, 32, 64);
                l_ = l_ * alpha + xs;
            }
        }

        // ---- merge the two key-halves of this pair through LDS ----
        if (half) {
            #pragma unroll
            for (int dt = 0; dt < 8; ++dt)
                #pragma unroll
                for (int r = 0; r < 4; ++r) smO[pslot][lane][dt * 4 + r] = accO[dt][r];
            smML[pslot][lane][0] = m_;
            smML[pslot][lane][1] = l_;
        }
        __syncthreads();
        if (!half) {
            // half=1 always has >=1 tile (it owns the diagonal) -> mB finite, lB > 0.
            // half=0 may be empty (nt==1): m_=-1e30 -> aA underflows to exactly 0.
            float mB = smML[pslot][lane][0], lB = smML[pslot][lane][1];
            float mN = fmaxf(m_, mB);
            float aA = __builtin_amdgcn_exp2f(m_ - mN);
            float aB = __builtin_amdgcn_exp2f(mB - mN);
            float inv = 1.0f / (l_ * aA + lB * aB);
            #pragma unroll
            for (int dt = 0; dt < 8; ++dt) {
                alignas(8) __hip_bfloat16 o[4];
                #pragma unroll
                for (int r = 0; r < 4; ++r)
                    o[r] = __float2bfloat16((accO[dt][r] * aA + smO[pslot][lane][dt * 4 + r] * aB) * inv);
                // O^T[d][q]: lane writes 4 consecutive d at row t=qg
                *reinterpret_cast<ushort4*>(&ctx[(size_t)qg * Q_SZ + h * HEAD_DIM + dt * 16 + quad * 4]) =
                    *reinterpret_cast<const ushort4*>(o);
            }
        }
        __syncthreads();   // smO/smML reused next pass
    }
}

extern "C" void kernel_launch(void* const* d_in, const int* in_sizes, int n_in,
                              void* d_out, int out_size, void* d_ws, size_t ws_size,
                              hipStream_t stream) {
    (void)in_sizes; (void)n_in; (void)out_size; (void)ws_size;
    const int*   positions = (const int*)d_in[0];
    const float* hidden    = (const float*)d_in[1];
    const float* w_qkv     = (const float*)d_in[2];
    const float* b_qkv     = (const float*)d_in[3];
    const float* w_dense   = (const float*)d_in[4];
    float* out = (float*)d_out;

    char* ws = (char*)d_ws;
    __hip_bfloat16* h_bf   = (__hip_bfloat16*)ws; ws += (size_t)T_SEQ * HIDDEN_SZ * 2;
    __hip_bfloat16* wqkvT  = (__hip_bfloat16*)ws; ws += (size_t)QKV_DIM * HIDDEN_SZ * 2;
    __hip_bfloat16* wdT    = (__hip_bfloat16*)ws; ws += (size_t)HIDDEN_SZ * HIDDEN_SZ * 2;
    __hip_bfloat16* qkv_bf = (__hip_bfloat16*)ws; ws += (size_t)T_SEQ * QKV_DIM * 2;
    __hip_bfloat16* q_bf   = (__hip_bfloat16*)ws; ws += (size_t)NUM_HEADS * T_SEQ * HEAD_DIM * 2;
    __hip_bfloat16* k_bf   = (__hip_bfloat16*)ws; ws += (size_t)KV_GROUPS * T_SEQ * HEAD_DIM * 2;
    __hip_bfloat16* vT_bf  = (__hip_bfloat16*)ws; ws += (size_t)KV_GROUPS * HEAD_DIM * T_SEQ * 2;
    __hip_bfloat16* ctx_bf = h_bf;  // h_bf dead after QKV GEMM; reuse for ctx

    // 1) hidden fp32 -> bf16
    convert_bf16_kernel<<<(T_SEQ * HIDDEN_SZ) / (256 * 4), 256, 0, stream>>>(hidden, h_bf, T_SEQ * HIDDEN_SZ);
    // 2) weights fp32 [K][N] -> bf16 [N][K]
    transpose_convert_kernel<<<dim3(QKV_DIM / 64, HIDDEN_SZ / 64), 256, 0, stream>>>(w_qkv, wqkvT, HIDDEN_SZ, QKV_DIM);
    transpose_convert_kernel<<<dim3(HIDDEN_SZ / 64, HIDDEN_SZ / 64), 256, 0, stream>>>(w_dense, wdT, HIDDEN_SZ, HIDDEN_SZ);
    // 3) QKV GEMM (+bias) -> bf16 qkv   (grid 36*16=576 blocks, %8==0 for XCD swizzle)
    gemm_bf16_kernel<__hip_bfloat16><<<dim3(QKV_DIM / 128, T_SEQ / 128), 256, 0, stream>>>(
        h_bf, wqkvT, b_qkv, qkv_bf, T_SEQ, QKV_DIM, HIDDEN_SZ);
    // 4) RoPE + relayout: Q row-major (pre-scaled), K/V frag-major for coalesced flash loads
    rope_reorg_kernel<<<dim3(T_SEQ, NUM_HEADS + 2 * KV_GROUPS), 64, 0, stream>>>(
        qkv_bf, positions, q_bf, k_bf, vT_bf);
    // 5) causal GQA flash attention (split-K, frag-major K/V) -> ctx bf16 [t][h*128+d]
    flash_attn_kernel<<<dim3(32, NUM_HEADS), 256, 0, stream>>>(q_bf, k_bf, vT_bf, ctx_bf);
    // 6) dense GEMM -> fp32 out   (grid 32*16=512 blocks, %8==0 for XCD swizzle)
    gemm_bf16_kernel<float><<<dim3(HIDDEN_SZ / 128, T_SEQ / 128), 256, 0, stream>>>(
        ctx_bf, wdT, nullptr, out, T_SEQ, HIDDEN_SZ, HIDDEN_SZ);
}